// Round 1
// baseline (6941.403 us; speedup 1.0000x reference)
//
#include <hip/hip_runtime.h>
#include <cstdint>
#include <cstddef>

// Problem constants (match reference)
#define P_NODES 100000
#define A_NODES 50000
#define IN_CH   128
#define H_CH    256
#define OUT_CH  349
#define NE_W    600000
#define NE_C    1000000

// ---------------------------------------------------------------------------
// Classic 64x64 LDS-tiled fp32 GEMM: C[M,N] = A[M,K] @ B[K,N] (+ bias[N])
// 256 threads = 16x16, each computes a 4x4 micro-tile. K must be %16 == 0.
// ---------------------------------------------------------------------------
__global__ __launch_bounds__(256) void gemm_bias_kernel(
    const float* __restrict__ A, const float* __restrict__ B,
    const float* __restrict__ bias, float* __restrict__ C,
    int M, int N, int K)
{
    __shared__ float As[16][65];  // As[k][m], +1 pad breaks stride-64 write conflicts
    __shared__ float Bs[16][65];  // Bs[k][n]

    const int tid = threadIdx.x;
    const int tm  = tid >> 4;     // 0..15
    const int tn  = tid & 15;     // 0..15
    const int blockM = blockIdx.y * 64;
    const int blockN = blockIdx.x * 64;

    float acc[4][4];
#pragma unroll
    for (int i = 0; i < 4; ++i)
#pragma unroll
        for (int j = 0; j < 4; ++j) acc[i][j] = 0.f;

    for (int k0 = 0; k0 < K; k0 += 16) {
        // A tile: 64 rows x 16 k. idx: m = idx/16, k = idx%16
#pragma unroll
        for (int i = 0; i < 4; ++i) {
            int idx = tid + i * 256;
            int m = idx >> 4, k = idx & 15;
            int gm = blockM + m;
            float v = 0.f;
            if (gm < M) v = A[(size_t)gm * K + k0 + k];
            As[k][m] = v;
        }
        // B tile: 16 k x 64 n. idx: k = idx/64, n = idx%64 (coalesced on n)
#pragma unroll
        for (int i = 0; i < 4; ++i) {
            int idx = tid + i * 256;
            int k = idx >> 6, n = idx & 63;
            int gn = blockN + n;
            float v = 0.f;
            if (gn < N) v = B[(size_t)(k0 + k) * N + gn];
            Bs[k][n] = v;
        }
        __syncthreads();
#pragma unroll
        for (int k = 0; k < 16; ++k) {
            float a[4], b[4];
#pragma unroll
            for (int i = 0; i < 4; ++i) a[i] = As[k][tm * 4 + i];
#pragma unroll
            for (int j = 0; j < 4; ++j) b[j] = Bs[k][tn * 4 + j];
#pragma unroll
            for (int i = 0; i < 4; ++i)
#pragma unroll
                for (int j = 0; j < 4; ++j) acc[i][j] += a[i] * b[j];
        }
        __syncthreads();
    }

#pragma unroll
    for (int i = 0; i < 4; ++i) {
        int gm = blockM + tm * 4 + i;
        if (gm >= M) continue;
#pragma unroll
        for (int j = 0; j < 4; ++j) {
            int gn = blockN + tn * 4 + j;
            if (gn >= N) continue;
            float v = acc[i][j];
            if (bias) v += bias[gn];
            C[(size_t)gm * N + gn] = v;
        }
    }
}

// ---------------------------------------------------------------------------
// Edge-degree count (float, exact for small integer counts)
// ---------------------------------------------------------------------------
__global__ void count_kernel(const int* __restrict__ dst, float* __restrict__ cnt, int E)
{
    int e = blockIdx.x * blockDim.x + threadIdx.x;
    if (e < E) atomicAdd(&cnt[dst[e]], 1.0f);
}

// cnt -> 1/max(cnt,1)
__global__ void inv_kernel(float* __restrict__ cnt, int n)
{
    int i = blockIdx.x * blockDim.x + threadIdx.x;
    if (i < n) cnt[i] = 1.0f / fmaxf(cnt[i], 1.0f);
}

// ---------------------------------------------------------------------------
// Scatter-add aggregation: out[dst[e]] += T[src[e]] * inv_cnt[dst[e]]
// One block per edge; threads cover the D features (D = 256 or 349).
// ---------------------------------------------------------------------------
__global__ __launch_bounds__(256) void scatter_kernel(
    const float* __restrict__ T, const int* __restrict__ src,
    const int* __restrict__ dst, const float* __restrict__ inv_cnt,
    float* __restrict__ out, int D)
{
    int e = blockIdx.x;
    int s = src[e];
    int d = dst[e];
    float w = inv_cnt[d];
    const float* trow = T + (size_t)s * D;
    float* orow = out + (size_t)d * D;
    for (int f = threadIdx.x; f < D; f += 256) {
        atomicAdd(&orow[f], trow[f] * w);
    }
}

__global__ void relu_kernel(float* __restrict__ x, size_t n)
{
    size_t i = (size_t)blockIdx.x * blockDim.x + threadIdx.x;
    if (i < n) x[i] = fmaxf(x[i], 0.f);
}

// In-place per-row log_softmax, one 64-lane wave per row
__global__ __launch_bounds__(64) void log_softmax_kernel(float* __restrict__ x, int N)
{
    const int row = blockIdx.x;
    const int lane = threadIdx.x;
    float* xr = x + (size_t)row * N;

    float m = -3.402823466e38f;
    for (int j = lane; j < N; j += 64) m = fmaxf(m, xr[j]);
#pragma unroll
    for (int off = 32; off > 0; off >>= 1) m = fmaxf(m, __shfl_down(m, off));
    m = __shfl(m, 0);

    float s = 0.f;
    for (int j = lane; j < N; j += 64) s += __expf(xr[j] - m);
#pragma unroll
    for (int off = 32; off > 0; off >>= 1) s += __shfl_down(s, off);
    s = __shfl(s, 0);

    float lse = m + __logf(s);
    for (int j = lane; j < N; j += 64) xr[j] = xr[j] - lse;
}

// ---------------------------------------------------------------------------
extern "C" void kernel_launch(void* const* d_in, const int* in_sizes, int n_in,
                              void* d_out, int out_size, void* d_ws, size_t ws_size,
                              hipStream_t stream)
{
    const float* x_paper = (const float*)d_in[0];
    const float* emb_a   = (const float*)d_in[1];
    const float* lin_w   = (const float*)d_in[2];
    const float* lin_b   = (const float*)d_in[3];
    const float* r0p_w   = (const float*)d_in[4];
    const float* r0p_b   = (const float*)d_in[5];
    const float* r0a_w   = (const float*)d_in[6];
    const float* r0a_b   = (const float*)d_in[7];
    const float* c0_wr   = (const float*)d_in[8];
    const float* c0_ci   = (const float*)d_in[9];
    const float* c0_rv   = (const float*)d_in[10];
    const float* r1_w    = (const float*)d_in[11];
    const float* r1_b    = (const float*)d_in[12];
    const float* c1_wr   = (const float*)d_in[13];
    const float* c1_ci   = (const float*)d_in[14];
    const int*   w_src   = (const int*)d_in[15];
    const int*   w_dst   = (const int*)d_in[16];
    const int*   c_src   = (const int*)d_in[17];
    const int*   c_dst   = (const int*)d_in[18];
    const int*   r_src   = (const int*)d_in[19];
    const int*   r_dst   = (const int*)d_in[20];

    // Workspace layout (fp32)
    float* ws    = (float*)d_ws;
    float* h_p   = ws;                                   // P x H
    float* out_p = h_p   + (size_t)P_NODES * H_CH;       // P x H
    float* t     = out_p + (size_t)P_NODES * H_CH;       // up to P x OUT
    float* out_a = t     + (size_t)P_NODES * OUT_CH;     // A x H
    float* cnt_w = out_a + (size_t)A_NODES * H_CH;       // P
    float* cnt_c = cnt_w + P_NODES;                      // P
    float* cnt_r = cnt_c + P_NODES;                      // A
    float* logits = (float*)d_out;                       // P x OUT (in-place softmax)

    // --- degree counts -> inverse ---
    hipMemsetAsync(cnt_w, 0, (size_t)(2 * P_NODES + A_NODES) * sizeof(float), stream);
    count_kernel<<<(NE_W + 255) / 256, 256, 0, stream>>>(w_dst, cnt_w, NE_W);
    count_kernel<<<(NE_C + 255) / 256, 256, 0, stream>>>(c_dst, cnt_c, NE_C);
    count_kernel<<<(NE_W + 255) / 256, 256, 0, stream>>>(r_dst, cnt_r, NE_W);
    inv_kernel<<<(2 * P_NODES + A_NODES + 255) / 256, 256, 0, stream>>>(cnt_w, 2 * P_NODES + A_NODES);

    dim3 blk(256);
    auto gemm = [&](const float* A, const float* B, const float* bias, float* C,
                    int M, int N, int K) {
        dim3 grid((N + 63) / 64, (M + 63) / 64);
        gemm_bias_kernel<<<grid, blk, 0, stream>>>(A, B, bias, C, M, N, K);
    };

    // --- layer 0 (uses linearity: mean_agg(h)@W == mean_agg(h@W)) ---
    gemm(x_paper, lin_w, lin_b, h_p, P_NODES, H_CH, IN_CH);            // h_p = x@lin + b
    gemm(h_p, r0p_w, r0p_b, out_p, P_NODES, H_CH, H_CH);               // out_p = root
    gemm(emb_a, c0_wr, nullptr, t, A_NODES, H_CH, H_CH);               // t = emb@W_writes
    scatter_kernel<<<NE_W, 256, 0, stream>>>(t, w_src, w_dst, cnt_w, out_p, H_CH);
    gemm(h_p, c0_ci, nullptr, t, P_NODES, H_CH, H_CH);                 // t = h_p@W_cites
    scatter_kernel<<<NE_C, 256, 0, stream>>>(t, c_src, c_dst, cnt_c, out_p, H_CH);
    gemm(emb_a, r0a_w, r0a_b, out_a, A_NODES, H_CH, H_CH);             // out_a = root
    gemm(h_p, c0_rv, nullptr, t, P_NODES, H_CH, H_CH);                 // t = h_p@W_revw
    scatter_kernel<<<NE_W, 256, 0, stream>>>(t, r_src, r_dst, cnt_r, out_a, H_CH);

    relu_kernel<<<((size_t)P_NODES * H_CH + 255) / 256, 256, 0, stream>>>(out_p, (size_t)P_NODES * H_CH);
    relu_kernel<<<((size_t)A_NODES * H_CH + 255) / 256, 256, 0, stream>>>(out_a, (size_t)A_NODES * H_CH);

    // --- layer 1 (out_p/out_a are now the relu'd hidden states) ---
    gemm(out_p, r1_w, r1_b, logits, P_NODES, OUT_CH, H_CH);            // root
    gemm(out_a, c1_wr, nullptr, t, A_NODES, OUT_CH, H_CH);             // t = h_a@W_writes
    scatter_kernel<<<NE_W, 256, 0, stream>>>(t, w_src, w_dst, cnt_w, logits, OUT_CH);
    gemm(out_p, c1_ci, nullptr, t, P_NODES, OUT_CH, H_CH);             // t = h_p@W_cites
    scatter_kernel<<<NE_C, 256, 0, stream>>>(t, c_src, c_dst, cnt_c, logits, OUT_CH);

    // --- log_softmax in place on d_out ---
    log_softmax_kernel<<<P_NODES, 64, 0, stream>>>(logits, OUT_CH);
}

// Round 2
// 3763.553 us; speedup vs baseline: 1.8444x; 1.8444x over previous
//
#include <hip/hip_runtime.h>
#include <cstdint>
#include <cstddef>

// Problem constants (match reference)
#define P_NODES 100000
#define A_NODES 50000
#define IN_CH   128
#define H_CH    256
#define OUT_CH  349
#define NE_W    600000
#define NE_C    1000000

#define SCAN_BS 512

// ---------------------------------------------------------------------------
// Classic 64x64 LDS-tiled fp32 GEMM: C[M,N] = [C +] A[M,K] @ B[K,N] (+ bias)
// 256 threads = 16x16, each computes a 4x4 micro-tile. K must be %16 == 0.
// ---------------------------------------------------------------------------
__global__ __launch_bounds__(256) void gemm_bias_kernel(
    const float* __restrict__ A, const float* __restrict__ B,
    const float* __restrict__ bias, float* __restrict__ C,
    int M, int N, int K, int accum)
{
    __shared__ float As[16][65];
    __shared__ float Bs[16][65];

    const int tid = threadIdx.x;
    const int tm  = tid >> 4;
    const int tn  = tid & 15;
    const int blockM = blockIdx.y * 64;
    const int blockN = blockIdx.x * 64;

    float acc[4][4];
#pragma unroll
    for (int i = 0; i < 4; ++i)
#pragma unroll
        for (int j = 0; j < 4; ++j) acc[i][j] = 0.f;

    for (int k0 = 0; k0 < K; k0 += 16) {
#pragma unroll
        for (int i = 0; i < 4; ++i) {
            int idx = tid + i * 256;
            int m = idx >> 4, k = idx & 15;
            int gm = blockM + m;
            float v = 0.f;
            if (gm < M) v = A[(size_t)gm * K + k0 + k];
            As[k][m] = v;
        }
#pragma unroll
        for (int i = 0; i < 4; ++i) {
            int idx = tid + i * 256;
            int k = idx >> 6, n = idx & 63;
            int gn = blockN + n;
            float v = 0.f;
            if (gn < N) v = B[(size_t)(k0 + k) * N + gn];
            Bs[k][n] = v;
        }
        __syncthreads();
#pragma unroll
        for (int k = 0; k < 16; ++k) {
            float a[4], b[4];
#pragma unroll
            for (int i = 0; i < 4; ++i) a[i] = As[k][tm * 4 + i];
#pragma unroll
            for (int j = 0; j < 4; ++j) b[j] = Bs[k][tn * 4 + j];
#pragma unroll
            for (int i = 0; i < 4; ++i)
#pragma unroll
                for (int j = 0; j < 4; ++j) acc[i][j] += a[i] * b[j];
        }
        __syncthreads();
    }

#pragma unroll
    for (int i = 0; i < 4; ++i) {
        int gm = blockM + tm * 4 + i;
        if (gm >= M) continue;
#pragma unroll
        for (int j = 0; j < 4; ++j) {
            int gn = blockN + tn * 4 + j;
            if (gn >= N) continue;
            float v = acc[i][j];
            if (bias) v += bias[gn];
            size_t off = (size_t)gm * N + gn;
            if (accum) v += C[off];
            C[off] = v;
        }
    }
}

// ---------------------------------------------------------------------------
// CSR construction: degree count -> exclusive scan -> bucket fill
// ---------------------------------------------------------------------------
__global__ void deg_kernel(const int* __restrict__ dst, int* __restrict__ deg, int E)
{
    int e = blockIdx.x * blockDim.x + threadIdx.x;
    if (e < E) atomicAdd(&deg[dst[e]], 1);
}

__global__ __launch_bounds__(SCAN_BS) void scan_phase_a(
    const int* __restrict__ deg, int* __restrict__ ptr, int* __restrict__ blksum, int n)
{
    __shared__ int s[SCAN_BS];
    int tid = threadIdx.x;
    int i = blockIdx.x * SCAN_BS + tid;
    int v = (i < n) ? deg[i] : 0;
    s[tid] = v;
    __syncthreads();
    for (int off = 1; off < SCAN_BS; off <<= 1) {
        int t = 0;
        if (tid >= off) t = s[tid - off];
        __syncthreads();
        s[tid] += t;
        __syncthreads();
    }
    if (i < n) ptr[i] = s[tid] - v;               // exclusive prefix
    if (tid == SCAN_BS - 1) blksum[blockIdx.x] = s[tid];
}

__global__ __launch_bounds__(SCAN_BS) void scan_phase_b(int* __restrict__ blksum, int nb)
{
    __shared__ int s[SCAN_BS];
    int tid = threadIdx.x;
    int v = (tid < nb) ? blksum[tid] : 0;
    s[tid] = v;
    __syncthreads();
    for (int off = 1; off < SCAN_BS; off <<= 1) {
        int t = 0;
        if (tid >= off) t = s[tid - off];
        __syncthreads();
        s[tid] += t;
        __syncthreads();
    }
    if (tid < nb) blksum[tid] = s[tid] - v;       // exclusive block offsets, in place
}

__global__ void scan_phase_c(const int* __restrict__ deg, int* __restrict__ ptr,
                             const int* __restrict__ blkoff, int* __restrict__ cur,
                             float* __restrict__ inv, int n, int E)
{
    int i = blockIdx.x * blockDim.x + threadIdx.x;
    if (i < n) {
        int p = ptr[i] + blkoff[i / SCAN_BS];
        ptr[i] = p;
        cur[i] = p;
        inv[i] = 1.0f / fmaxf((float)deg[i], 1.0f);
    }
    if (i == 0) ptr[n] = E;
}

__global__ void fill_kernel(const int* __restrict__ src, const int* __restrict__ dst,
                            int* __restrict__ cur, int* __restrict__ idx, int E)
{
    int e = blockIdx.x * blockDim.x + threadIdx.x;
    if (e < E) {
        int pos = atomicAdd(&cur[dst[e]], 1);
        idx[pos] = src[e];
    }
}

// ---------------------------------------------------------------------------
// Gather aggregation, D = H_CH (256): one wave per dst row, float4 per lane.
// out[row] (+)= mean over in-edges of T[src].
// ---------------------------------------------------------------------------
__global__ __launch_bounds__(256) void gather_h_kernel(
    const float* __restrict__ T, const int* __restrict__ ptr, const int* __restrict__ idx,
    const float* __restrict__ inv, float* __restrict__ out, int R, int accum)
{
    int row = blockIdx.x * 4 + (threadIdx.x >> 6);
    if (row >= R) return;
    int lane = threadIdx.x & 63;
    int s = ptr[row], e = ptr[row + 1];
    float4 acc = {0.f, 0.f, 0.f, 0.f};
    for (int j = s; j < e; ++j) {
        const float4* tr = (const float4*)(T + (size_t)idx[j] * H_CH);
        float4 v = tr[lane];
        acc.x += v.x; acc.y += v.y; acc.z += v.z; acc.w += v.w;
    }
    float w = inv[row];
    float4* orow = (float4*)(out + (size_t)row * H_CH);
    float4 o;
    if (accum) {
        o = orow[lane];
        o.x += acc.x * w; o.y += acc.y * w; o.z += acc.z * w; o.w += acc.w * w;
    } else {
        o.x = acc.x * w; o.y = acc.y * w; o.z = acc.z * w; o.w = acc.w * w;
    }
    orow[lane] = o;
}

// ---------------------------------------------------------------------------
// Gather aggregation, D = OUT_CH (349): one block per dst row, accumulate.
// ---------------------------------------------------------------------------
__global__ __launch_bounds__(256) void gather_out_kernel(
    const float* __restrict__ T, const int* __restrict__ ptr, const int* __restrict__ idx,
    const float* __restrict__ inv, float* __restrict__ out, int R)
{
    __shared__ int sidx[256];
    int row = blockIdx.x;
    if (row >= R) return;
    int tid = threadIdx.x;
    int s = ptr[row], e = ptr[row + 1];
    float w = inv[row];
    float acc0 = 0.f, acc1 = 0.f;
    const int f0 = tid, f1 = tid + 256;
    for (int base = s; base < e; base += 256) {
        int m = min(256, e - base);
        __syncthreads();
        if (tid < m) sidx[tid] = idx[base + tid];
        __syncthreads();
        for (int j = 0; j < m; ++j) {
            const float* tr = T + (size_t)sidx[j] * OUT_CH;
            acc0 += tr[f0];
            if (f1 < OUT_CH) acc1 += tr[f1];
        }
    }
    float* orow = out + (size_t)row * OUT_CH;
    if (f0 < OUT_CH) orow[f0] += acc0 * w;
    if (f1 < OUT_CH) orow[f1] += acc1 * w;
}

__global__ void relu_kernel(float* __restrict__ x, size_t n)
{
    size_t i = (size_t)blockIdx.x * blockDim.x + threadIdx.x;
    if (i < n) x[i] = fmaxf(x[i], 0.f);
}

// In-place per-row log_softmax, one 64-lane wave per row
__global__ __launch_bounds__(64) void log_softmax_kernel(float* __restrict__ x, int N)
{
    const int row = blockIdx.x;
    const int lane = threadIdx.x;
    float* xr = x + (size_t)row * N;

    float m = -3.402823466e38f;
    for (int j = lane; j < N; j += 64) m = fmaxf(m, xr[j]);
#pragma unroll
    for (int off = 32; off > 0; off >>= 1) m = fmaxf(m, __shfl_down(m, off));
    m = __shfl(m, 0);

    float s = 0.f;
    for (int j = lane; j < N; j += 64) s += __expf(xr[j] - m);
#pragma unroll
    for (int off = 32; off > 0; off >>= 1) s += __shfl_down(s, off);
    s = __shfl(s, 0);

    float lse = m + __logf(s);
    for (int j = lane; j < N; j += 64) xr[j] = xr[j] - lse;
}

// ---------------------------------------------------------------------------
extern "C" void kernel_launch(void* const* d_in, const int* in_sizes, int n_in,
                              void* d_out, int out_size, void* d_ws, size_t ws_size,
                              hipStream_t stream)
{
    const float* x_paper = (const float*)d_in[0];
    const float* emb_a   = (const float*)d_in[1];
    const float* lin_w   = (const float*)d_in[2];
    const float* lin_b   = (const float*)d_in[3];
    const float* r0p_w   = (const float*)d_in[4];
    const float* r0p_b   = (const float*)d_in[5];
    const float* r0a_w   = (const float*)d_in[6];
    const float* r0a_b   = (const float*)d_in[7];
    const float* c0_wr   = (const float*)d_in[8];
    const float* c0_ci   = (const float*)d_in[9];
    const float* c0_rv   = (const float*)d_in[10];
    const float* r1_w    = (const float*)d_in[11];
    const float* r1_b    = (const float*)d_in[12];
    const float* c1_wr   = (const float*)d_in[13];
    const float* c1_ci   = (const float*)d_in[14];
    const int*   w_src   = (const int*)d_in[15];
    const int*   w_dst   = (const int*)d_in[16];
    const int*   c_src   = (const int*)d_in[17];
    const int*   c_dst   = (const int*)d_in[18];
    const int*   r_src   = (const int*)d_in[19];
    const int*   r_dst   = (const int*)d_in[20];

    // ---------------- workspace layout ----------------
    // floats: h_p/scratch (P*H), out_p (P*H), out_a (A*H), inv_w/c/r
    float* ws    = (float*)d_ws;
    float* h_p   = ws;                                   // P x H (also t_w / agg in layer 1)
    float* out_p = h_p   + (size_t)P_NODES * H_CH;
    float* out_a = out_p + (size_t)P_NODES * H_CH;
    float* inv_w = out_a + (size_t)A_NODES * H_CH;       // P
    float* inv_c = inv_w + P_NODES;                      // P
    float* inv_r = inv_c + P_NODES;                      // A
    float* fend  = inv_r + A_NODES;

    int* ip    = (int*)fend;
    int* deg_w = ip;                 ip += P_NODES;
    int* deg_c = ip;                 ip += P_NODES;
    int* deg_r = ip;                 ip += A_NODES;
    int* ptr_w = ip;                 ip += P_NODES + 1;
    int* ptr_c = ip;                 ip += P_NODES + 1;
    int* ptr_r = ip;                 ip += A_NODES + 1;
    int* cur_w = ip;                 ip += P_NODES;
    int* cur_c = ip;                 ip += P_NODES;
    int* cur_r = ip;                 ip += A_NODES;
    int* idx_w = ip;                 ip += NE_W;
    int* idx_c = ip;                 ip += NE_C;
    int* idx_r = ip;                 ip += NE_W;
    int* blk   = ip;                 ip += 1024;

    float* t0     = (float*)d_out;   // layer-0 scratch (P*OUT >= P*H); overwritten later
    float* logits = (float*)d_out;

    // ---------------- CSR builds ----------------
    hipMemsetAsync(deg_w, 0, (size_t)(2 * P_NODES + A_NODES) * sizeof(int), stream);
    deg_kernel<<<(NE_W + 255) / 256, 256, 0, stream>>>(w_dst, deg_w, NE_W);
    deg_kernel<<<(NE_C + 255) / 256, 256, 0, stream>>>(c_dst, deg_c, NE_C);
    deg_kernel<<<(NE_W + 255) / 256, 256, 0, stream>>>(r_dst, deg_r, NE_W);

    auto build_csr = [&](const int* src, const int* dst, int* deg, int* ptr, int* cur,
                         int* idx, float* inv, int n, int E) {
        int nb = (n + SCAN_BS - 1) / SCAN_BS;
        scan_phase_a<<<nb, SCAN_BS, 0, stream>>>(deg, ptr, blk, n);
        scan_phase_b<<<1, SCAN_BS, 0, stream>>>(blk, nb);
        scan_phase_c<<<(n + 255) / 256, 256, 0, stream>>>(deg, ptr, blk, cur, inv, n, E);
        fill_kernel<<<(E + 255) / 256, 256, 0, stream>>>(src, dst, cur, idx, E);
    };
    build_csr(w_src, w_dst, deg_w, ptr_w, cur_w, idx_w, inv_w, P_NODES, NE_W);
    build_csr(c_src, c_dst, deg_c, ptr_c, cur_c, idx_c, inv_c, P_NODES, NE_C);
    build_csr(r_src, r_dst, deg_r, ptr_r, cur_r, idx_r, inv_r, A_NODES, NE_W);

    dim3 blk256(256);
    auto gemm = [&](const float* A, const float* B, const float* bias, float* C,
                    int M, int N, int K, int accum) {
        dim3 grid((N + 63) / 64, (M + 63) / 64);
        gemm_bias_kernel<<<grid, blk256, 0, stream>>>(A, B, bias, C, M, N, K, accum);
    };
    auto gather_h = [&](const float* T, const int* ptr, const int* idx, const float* inv,
                        float* out, int R, int accum) {
        gather_h_kernel<<<(R + 3) / 4, 256, 0, stream>>>(T, ptr, idx, inv, out, R, accum);
    };

    // ---------------- layer 0 (mean_agg(h)@W == mean_agg(h@W)) ----------------
    gemm(x_paper, lin_w, lin_b, h_p, P_NODES, H_CH, IN_CH, 0);        // h_p = x@lin + b
    gemm(h_p, r0p_w, r0p_b, out_p, P_NODES, H_CH, H_CH, 0);           // root paper
    gemm(emb_a, c0_wr, nullptr, t0, A_NODES, H_CH, H_CH, 0);          // t0 = emb@W_writes
    gather_h(t0, ptr_w, idx_w, inv_w, out_p, P_NODES, 1);
    gemm(h_p, c0_ci, nullptr, t0, P_NODES, H_CH, H_CH, 0);            // t0 = h_p@W_cites
    gather_h(t0, ptr_c, idx_c, inv_c, out_p, P_NODES, 1);
    gemm(emb_a, r0a_w, r0a_b, out_a, A_NODES, H_CH, H_CH, 0);         // root author
    gemm(h_p, c0_rv, nullptr, t0, P_NODES, H_CH, H_CH, 0);            // t0 = h_p@W_revw
    gather_h(t0, ptr_r, idx_r, inv_r, out_a, A_NODES, 1);

    relu_kernel<<<((size_t)P_NODES * H_CH + 255) / 256, 256, 0, stream>>>(out_p, (size_t)P_NODES * H_CH);
    relu_kernel<<<((size_t)A_NODES * H_CH + 255) / 256, 256, 0, stream>>>(out_a, (size_t)A_NODES * H_CH);

    // ---------------- layer 1 ----------------
    // root: logits = out_p @ r1_w + b    (overwrites t0 region — t0 no longer needed)
    gemm(out_p, r1_w, r1_b, logits, P_NODES, OUT_CH, H_CH, 0);

    // writes: t_w = out_a @ c1_wr (A x OUT, fits in h_p region), gather into logits
    float* t_w = h_p;
    gemm(out_a, c1_wr, nullptr, t_w, A_NODES, OUT_CH, H_CH, 0);
    gather_out_kernel<<<P_NODES, 256, 0, stream>>>(t_w, ptr_w, idx_w, inv_w, logits, P_NODES);

    // cites: agg = mean_agg(out_p) (P x H, h_p region free again), then logits += agg @ c1_ci
    float* agg = h_p;
    gather_h(out_p, ptr_c, idx_c, inv_c, agg, P_NODES, 0);
    gemm(agg, c1_ci, nullptr, logits, P_NODES, OUT_CH, H_CH, 1);

    // ---------------- log_softmax in place ----------------
    log_softmax_kernel<<<P_NODES, 64, 0, stream>>>(logits, OUT_CH);
}

// Round 3
// 2062.875 us; speedup vs baseline: 3.3649x; 1.8244x over previous
//
#include <hip/hip_runtime.h>
#include <cstdint>
#include <cstddef>

// Problem constants (match reference)
#define P_NODES 100000
#define A_NODES 50000
#define IN_CH   128
#define H_CH    256
#define OUT_CH  349
#define NE_W    600000
#define NE_C    1000000

#define SCAN_BS 512

typedef unsigned short u16;
typedef unsigned int   u32;
typedef __bf16 bf16x8 __attribute__((ext_vector_type(8)));
typedef float  f32x4  __attribute__((ext_vector_type(4)));
typedef u16    u16x4  __attribute__((ext_vector_type(4)));
typedef u16    u16x8  __attribute__((ext_vector_type(8)));

// fp32 -> bf16 round-to-nearest-even
__device__ __forceinline__ u16 f2bf(float f) {
    u32 u = __builtin_bit_cast(u32, f);
    u += 0x7FFFu + ((u >> 16) & 1u);
    return (u16)(u >> 16);
}
__device__ __forceinline__ float bf2f(u16 v) {
    return __builtin_bit_cast(float, (u32)v << 16);
}

// ---------------------------------------------------------------------------
// MFMA bf16 GEMM: C[M,N] = [C +] A[M,K] @ W[K,N] (+ bias)
// A: row-major [M,K], fp32 or bf16(u16).  WT: bf16 W^T, row-major [N,K].
// Tile 128x128, BK=32, 256 threads = 4 waves; wave owns a 64x64 quadrant
// (4x4 grid of 16x16x32 MFMA tiles). LDS rows padded to 40 bf16 (80 B).
// ---------------------------------------------------------------------------
#define SA 40

template<typename TA, bool OUTBF>
__global__ __launch_bounds__(256) void mfma_gemm(
    const TA* __restrict__ A, const u16* __restrict__ WT,
    const float* __restrict__ bias, void* __restrict__ Cv,
    int M, int N, int K, int accum)
{
    __shared__ u16 Asl[128 * SA];
    __shared__ u16 Bsl[128 * SA];

    const int tid  = threadIdx.x;
    const int blockM = blockIdx.y * 128;
    const int blockN = blockIdx.x * 128;

    const int w    = tid >> 6;         // wave 0..3
    const int lane = tid & 63;
    const int m16  = lane & 15;
    const int quad = lane >> 4;
    const int wr   = (w >> 1) * 64;    // wave quadrant row
    const int wc   = (w & 1) * 64;     // wave quadrant col

    f32x4 acc[4][4];
#pragma unroll
    for (int i = 0; i < 4; ++i)
#pragma unroll
        for (int j = 0; j < 4; ++j) acc[i][j] = (f32x4){0.f, 0.f, 0.f, 0.f};

    const int rs = tid >> 3;          // 0..31 (staging row within pass)
    const int kk = (tid & 7) * 4;     // 0..28 (staging k offset)

    for (int k0 = 0; k0 < K; k0 += 32) {
        // ---- stage A tile: 128 x 32 -> bf16 LDS ----
#pragma unroll
        for (int p = 0; p < 4; ++p) {
            int r  = p * 32 + rs;
            int gm = blockM + r;
            u16x4 o;
            if (gm < M) {
                if constexpr (sizeof(TA) == 4) {
                    const float4 v = *(const float4*)((const float*)A + (size_t)gm * K + k0 + kk);
                    o[0] = f2bf(v.x); o[1] = f2bf(v.y); o[2] = f2bf(v.z); o[3] = f2bf(v.w);
                } else {
                    o = *(const u16x4*)((const u16*)A + (size_t)gm * K + k0 + kk);
                }
            } else {
                o = (u16x4){0, 0, 0, 0};
            }
            *(u16x4*)&Asl[r * SA + kk] = o;
        }
        // ---- stage B tile from WT[N][K]: rows n, 32 k -> bf16 LDS ----
#pragma unroll
        for (int p = 0; p < 4; ++p) {
            int n  = p * 32 + rs;
            int gn = blockN + n;
            u16x4 o;
            if (gn < N) o = *(const u16x4*)(WT + (size_t)gn * K + k0 + kk);
            else        o = (u16x4){0, 0, 0, 0};
            *(u16x4*)&Bsl[n * SA + kk] = o;
        }
        __syncthreads();

        // ---- fragments + MFMA ----
        bf16x8 af[4], bf[4];
#pragma unroll
        for (int mt = 0; mt < 4; ++mt) {
            int off = (wr + mt * 16 + m16) * SA + quad * 8;
            u16x4 a0 = *(const u16x4*)&Asl[off];
            u16x4 a1 = *(const u16x4*)&Asl[off + 4];
            u16x8 av = {a0[0], a0[1], a0[2], a0[3], a1[0], a1[1], a1[2], a1[3]};
            af[mt] = __builtin_bit_cast(bf16x8, av);
        }
#pragma unroll
        for (int nt = 0; nt < 4; ++nt) {
            int off = (wc + nt * 16 + m16) * SA + quad * 8;
            u16x4 b0 = *(const u16x4*)&Bsl[off];
            u16x4 b1 = *(const u16x4*)&Bsl[off + 4];
            u16x8 bv = {b0[0], b0[1], b0[2], b0[3], b1[0], b1[1], b1[2], b1[3]};
            bf[nt] = __builtin_bit_cast(bf16x8, bv);
        }
#pragma unroll
        for (int mt = 0; mt < 4; ++mt)
#pragma unroll
            for (int nt = 0; nt < 4; ++nt)
                acc[mt][nt] = __builtin_amdgcn_mfma_f32_16x16x32_bf16(
                    af[mt], bf[nt], acc[mt][nt], 0, 0, 0);
        __syncthreads();
    }

    // ---- epilogue: C/D layout col=lane&15, row=quad*4+reg ----
#pragma unroll
    for (int mt = 0; mt < 4; ++mt) {
#pragma unroll
        for (int nt = 0; nt < 4; ++nt) {
            int col = blockN + wc + nt * 16 + m16;
            if (col >= N) continue;
#pragma unroll
            for (int reg = 0; reg < 4; ++reg) {
                int row = blockM + wr + mt * 16 + quad * 4 + reg;
                if (row >= M) continue;
                float v = acc[mt][nt][reg];
                if (bias) v += bias[col];
                size_t off = (size_t)row * N + col;
                if constexpr (OUTBF) {
                    ((u16*)Cv)[off] = f2bf(v);
                } else {
                    float* C = (float*)Cv;
                    if (accum) v += C[off];
                    C[off] = v;
                }
            }
        }
    }
}

// ---------------------------------------------------------------------------
// Weight transpose + bf16 convert: W[K,N] fp32 -> WT[N,K] bf16
// ---------------------------------------------------------------------------
__global__ void transpose_w_kernel(const float* __restrict__ W, u16* __restrict__ WT,
                                   int K, int N)
{
    int i = blockIdx.x * blockDim.x + threadIdx.x;
    if (i < K * N) {
        int k = i / N, n = i - k * N;
        WT[(size_t)n * K + k] = f2bf(W[i]);
    }
}

// ---------------------------------------------------------------------------
// CSR construction: degree count -> exclusive scan -> bucket fill
// ---------------------------------------------------------------------------
__global__ void deg_kernel(const int* __restrict__ dst, int* __restrict__ deg, int E)
{
    int e = blockIdx.x * blockDim.x + threadIdx.x;
    if (e < E) atomicAdd(&deg[dst[e]], 1);
}

__global__ __launch_bounds__(SCAN_BS) void scan_phase_a(
    const int* __restrict__ deg, int* __restrict__ ptr, int* __restrict__ blksum, int n)
{
    __shared__ int s[SCAN_BS];
    int tid = threadIdx.x;
    int i = blockIdx.x * SCAN_BS + tid;
    int v = (i < n) ? deg[i] : 0;
    s[tid] = v;
    __syncthreads();
    for (int off = 1; off < SCAN_BS; off <<= 1) {
        int t = 0;
        if (tid >= off) t = s[tid - off];
        __syncthreads();
        s[tid] += t;
        __syncthreads();
    }
    if (i < n) ptr[i] = s[tid] - v;
    if (tid == SCAN_BS - 1) blksum[blockIdx.x] = s[tid];
}

__global__ __launch_bounds__(SCAN_BS) void scan_phase_b(int* __restrict__ blksum, int nb)
{
    __shared__ int s[SCAN_BS];
    int tid = threadIdx.x;
    int v = (tid < nb) ? blksum[tid] : 0;
    s[tid] = v;
    __syncthreads();
    for (int off = 1; off < SCAN_BS; off <<= 1) {
        int t = 0;
        if (tid >= off) t = s[tid - off];
        __syncthreads();
        s[tid] += t;
        __syncthreads();
    }
    if (tid < nb) blksum[tid] = s[tid] - v;
}

__global__ void scan_phase_c(const int* __restrict__ deg, int* __restrict__ ptr,
                             const int* __restrict__ blkoff, int* __restrict__ cur,
                             float* __restrict__ inv, int n, int E)
{
    int i = blockIdx.x * blockDim.x + threadIdx.x;
    if (i < n) {
        int p = ptr[i] + blkoff[i / SCAN_BS];
        ptr[i] = p;
        cur[i] = p;
        inv[i] = 1.0f / fmaxf((float)deg[i], 1.0f);
    }
    if (i == 0) ptr[n] = E;
}

__global__ void fill_kernel(const int* __restrict__ src, const int* __restrict__ dst,
                            int* __restrict__ cur, int* __restrict__ idx, int E)
{
    int e = blockIdx.x * blockDim.x + threadIdx.x;
    if (e < E) {
        int pos = atomicAdd(&cur[dst[e]], 1);
        idx[pos] = src[e];
    }
}

// ---------------------------------------------------------------------------
// Gather aggregation, D=256, T in bf16. One wave per dst row, u16x4/lane.
// ---------------------------------------------------------------------------
__global__ __launch_bounds__(256) void gather_h_f32(
    const u16* __restrict__ T, const int* __restrict__ ptr, const int* __restrict__ idx,
    const float* __restrict__ inv, float* __restrict__ out, int R, int accum)
{
    int row = blockIdx.x * 4 + (threadIdx.x >> 6);
    if (row >= R) return;
    int lane = threadIdx.x & 63;
    int s = ptr[row], e = ptr[row + 1];
    float a0 = 0.f, a1 = 0.f, a2 = 0.f, a3 = 0.f;
    for (int j = s; j < e; ++j) {
        u16x4 t = *(const u16x4*)(T + (size_t)idx[j] * H_CH + lane * 4);
        a0 += bf2f(t[0]); a1 += bf2f(t[1]); a2 += bf2f(t[2]); a3 += bf2f(t[3]);
    }
    float wgt = inv[row];
    float4* orow = (float4*)(out + (size_t)row * H_CH);
    float4 o;
    if (accum) {
        o = orow[lane];
        o.x += a0 * wgt; o.y += a1 * wgt; o.z += a2 * wgt; o.w += a3 * wgt;
    } else {
        o.x = a0 * wgt; o.y = a1 * wgt; o.z = a2 * wgt; o.w = a3 * wgt;
    }
    orow[lane] = o;
}

__global__ __launch_bounds__(256) void gather_h_bf16(
    const u16* __restrict__ T, const int* __restrict__ ptr, const int* __restrict__ idx,
    const float* __restrict__ inv, u16* __restrict__ out, int R, int accum)
{
    int row = blockIdx.x * 4 + (threadIdx.x >> 6);
    if (row >= R) return;
    int lane = threadIdx.x & 63;
    int s = ptr[row], e = ptr[row + 1];
    float a0 = 0.f, a1 = 0.f, a2 = 0.f, a3 = 0.f;
    for (int j = s; j < e; ++j) {
        u16x4 t = *(const u16x4*)(T + (size_t)idx[j] * H_CH + lane * 4);
        a0 += bf2f(t[0]); a1 += bf2f(t[1]); a2 += bf2f(t[2]); a3 += bf2f(t[3]);
    }
    float wgt = inv[row];
    u16x4* orow = (u16x4*)(out + (size_t)row * H_CH);
    u16x4 o;
    if (accum) {
        u16x4 c = orow[lane];
        o[0] = f2bf(bf2f(c[0]) + a0 * wgt);
        o[1] = f2bf(bf2f(c[1]) + a1 * wgt);
        o[2] = f2bf(bf2f(c[2]) + a2 * wgt);
        o[3] = f2bf(bf2f(c[3]) + a3 * wgt);
    } else {
        o[0] = f2bf(a0 * wgt); o[1] = f2bf(a1 * wgt);
        o[2] = f2bf(a2 * wgt); o[3] = f2bf(a3 * wgt);
    }
    orow[lane] = o;
}

// ---------------------------------------------------------------------------
// Gather aggregation, D = OUT_CH (349), T in bf16, accumulate into fp32 out.
// ---------------------------------------------------------------------------
__global__ __launch_bounds__(256) void gather_out_kernel(
    const u16* __restrict__ T, const int* __restrict__ ptr, const int* __restrict__ idx,
    const float* __restrict__ inv, float* __restrict__ out, int R)
{
    __shared__ int sidx[256];
    int row = blockIdx.x;
    if (row >= R) return;
    int tid = threadIdx.x;
    int s = ptr[row], e = ptr[row + 1];
    float wgt = inv[row];
    float acc0 = 0.f, acc1 = 0.f;
    const int f0 = tid, f1 = tid + 256;
    for (int base = s; base < e; base += 256) {
        int m = min(256, e - base);
        __syncthreads();
        if (tid < m) sidx[tid] = idx[base + tid];
        __syncthreads();
        for (int j = 0; j < m; ++j) {
            const u16* tr = T + (size_t)sidx[j] * OUT_CH;
            acc0 += bf2f(tr[f0]);
            if (f1 < OUT_CH) acc1 += bf2f(tr[f1]);
        }
    }
    float* orow = out + (size_t)row * OUT_CH;
    if (f0 < OUT_CH) orow[f0] += acc0 * wgt;
    if (f1 < OUT_CH) orow[f1] += acc1 * wgt;
}

// relu fp32 -> bf16 copy (fp32 source dead afterwards)
__global__ void relu_f32_to_bf16(const float* __restrict__ x, u16* __restrict__ y, size_t n)
{
    size_t i = (size_t)blockIdx.x * blockDim.x + threadIdx.x;
    if (i < n) y[i] = f2bf(fmaxf(x[i], 0.f));
}

// relu on bf16 in place: negative (sign bit set) -> 0
__global__ void relu_bf16(u16* __restrict__ x, size_t n)
{
    size_t i = (size_t)blockIdx.x * blockDim.x + threadIdx.x;
    if (i < n) x[i] = (x[i] & 0x8000u) ? (u16)0 : x[i];
}

// In-place per-row log_softmax, one 64-lane wave per row
__global__ __launch_bounds__(64) void log_softmax_kernel(float* __restrict__ x, int N)
{
    const int row = blockIdx.x;
    const int lane = threadIdx.x;
    float* xr = x + (size_t)row * N;

    float m = -3.402823466e38f;
    for (int j = lane; j < N; j += 64) m = fmaxf(m, xr[j]);
#pragma unroll
    for (int off = 32; off > 0; off >>= 1) m = fmaxf(m, __shfl_down(m, off));
    m = __shfl(m, 0);

    float s = 0.f;
    for (int j = lane; j < N; j += 64) s += __expf(xr[j] - m);
#pragma unroll
    for (int off = 32; off > 0; off >>= 1) s += __shfl_down(s, off);
    s = __shfl(s, 0);

    float lse = m + __logf(s);
    for (int j = lane; j < N; j += 64) xr[j] = xr[j] - lse;
}

// ---------------------------------------------------------------------------
extern "C" void kernel_launch(void* const* d_in, const int* in_sizes, int n_in,
                              void* d_out, int out_size, void* d_ws, size_t ws_size,
                              hipStream_t stream)
{
    const float* x_paper = (const float*)d_in[0];
    const float* emb_a   = (const float*)d_in[1];
    const float* lin_w   = (const float*)d_in[2];
    const float* lin_b   = (const float*)d_in[3];
    const float* r0p_w   = (const float*)d_in[4];
    const float* r0p_b   = (const float*)d_in[5];
    const float* r0a_w   = (const float*)d_in[6];
    const float* r0a_b   = (const float*)d_in[7];
    const float* c0_wr   = (const float*)d_in[8];
    const float* c0_ci   = (const float*)d_in[9];
    const float* c0_rv   = (const float*)d_in[10];
    const float* r1_w    = (const float*)d_in[11];
    const float* r1_b    = (const float*)d_in[12];
    const float* c1_wr   = (const float*)d_in[13];
    const float* c1_ci   = (const float*)d_in[14];
    const int*   w_src   = (const int*)d_in[15];
    const int*   w_dst   = (const int*)d_in[16];
    const int*   c_src   = (const int*)d_in[17];
    const int*   c_dst   = (const int*)d_in[18];
    const int*   r_src   = (const int*)d_in[19];
    const int*   r_dst   = (const int*)d_in[20];

    // ---------------- workspace layout ----------------
    const size_t PH = (size_t)P_NODES * H_CH;
    const size_t AH = (size_t)A_NODES * H_CH;

    float* out_p = (float*)d_ws;                 // P x H fp32 accumulation target
    float* inv_w = out_p + PH;                   // P
    float* inv_c = inv_w + P_NODES;              // P
    float* inv_r = inv_c + P_NODES;              // A
    u16* h_p_bf   = (u16*)(inv_r + A_NODES);     // P x H bf16  (later t_w / agg)
    u16* t0_bf    = h_p_bf + PH;                 // P x H bf16  (later out_p_bf)
    u16* out_a_bf = t0_bf + PH;                  // A x H bf16
    u16* wt       = out_a_bf + AH;               // transposed bf16 weights
    u16* wt_lin  = wt;                     // 128*256  = 32768
    u16* wt_r0p  = wt_lin  + 32768;        // 65536
    u16* wt_r0a  = wt_r0p  + 65536;
    u16* wt_c0wr = wt_r0a  + 65536;
    u16* wt_c0ci = wt_c0wr + 65536;
    u16* wt_c0rv = wt_c0ci + 65536;
    u16* wt_r1   = wt_c0rv + 65536;        // 256*349 = 89344
    u16* wt_c1wr = wt_r1   + 89344;
    u16* wt_c1ci = wt_c1wr + 89344;

    int* ip    = (int*)(wt_c1ci + 89344);
    int* deg_w = ip;                 ip += P_NODES;
    int* deg_c = ip;                 ip += P_NODES;
    int* deg_r = ip;                 ip += A_NODES;
    int* ptr_w = ip;                 ip += P_NODES + 1;
    int* ptr_c = ip;                 ip += P_NODES + 1;
    int* ptr_r = ip;                 ip += A_NODES + 1;
    int* cur_w = ip;                 ip += P_NODES;
    int* cur_c = ip;                 ip += P_NODES;
    int* cur_r = ip;                 ip += A_NODES;
    int* idx_w = ip;                 ip += NE_W;
    int* idx_c = ip;                 ip += NE_C;
    int* idx_r = ip;                 ip += NE_W;
    int* blk   = ip;                 ip += 1024;

    u16* t_w_bf   = h_p_bf;   // A x OUT bf16, layer 1 (h_p dead)
    u16* agg_bf   = h_p_bf;   // P x H bf16, layer 1 (t_w dead)
    u16* out_p_bf = t0_bf;    // P x H bf16, after layer-0 gathers (t0 dead)
    float* logits = (float*)d_out;

    // ---------------- weight transposes (bf16 W^T) ----------------
    auto twp = [&](const float* W, u16* WT, int K, int N) {
        transpose_w_kernel<<<(K * N + 255) / 256, 256, 0, stream>>>(W, WT, K, N);
    };
    twp(lin_w,  wt_lin,  IN_CH, H_CH);
    twp(r0p_w,  wt_r0p,  H_CH, H_CH);
    twp(r0a_w,  wt_r0a,  H_CH, H_CH);
    twp(c0_wr,  wt_c0wr, H_CH, H_CH);
    twp(c0_ci,  wt_c0ci, H_CH, H_CH);
    twp(c0_rv,  wt_c0rv, H_CH, H_CH);
    twp(r1_w,   wt_r1,   H_CH, OUT_CH);
    twp(c1_wr,  wt_c1wr, H_CH, OUT_CH);
    twp(c1_ci,  wt_c1ci, H_CH, OUT_CH);

    // ---------------- CSR builds ----------------
    hipMemsetAsync(deg_w, 0, (size_t)(2 * P_NODES + A_NODES) * sizeof(int), stream);
    deg_kernel<<<(NE_W + 255) / 256, 256, 0, stream>>>(w_dst, deg_w, NE_W);
    deg_kernel<<<(NE_C + 255) / 256, 256, 0, stream>>>(c_dst, deg_c, NE_C);
    deg_kernel<<<(NE_W + 255) / 256, 256, 0, stream>>>(r_dst, deg_r, NE_W);

    auto build_csr = [&](const int* src, const int* dst, int* deg, int* ptr, int* cur,
                         int* idx, float* inv, int n, int E) {
        int nb = (n + SCAN_BS - 1) / SCAN_BS;
        scan_phase_a<<<nb, SCAN_BS, 0, stream>>>(deg, ptr, blk, n);
        scan_phase_b<<<1, SCAN_BS, 0, stream>>>(blk, nb);
        scan_phase_c<<<(n + 255) / 256, 256, 0, stream>>>(deg, ptr, blk, cur, inv, n, E);
        fill_kernel<<<(E + 255) / 256, 256, 0, stream>>>(src, dst, cur, idx, E);
    };
    build_csr(w_src, w_dst, deg_w, ptr_w, cur_w, idx_w, inv_w, P_NODES, NE_W);
    build_csr(c_src, c_dst, deg_c, ptr_c, cur_c, idx_c, inv_c, P_NODES, NE_C);
    build_csr(r_src, r_dst, deg_r, ptr_r, cur_r, idx_r, inv_r, A_NODES, NE_W);

    // ---------------- GEMM + gather pipeline ----------------
    auto gemm_f = [&](const float* A, const u16* WT, const float* bias, void* C,
                      int M, int N, int K, int accum, bool outbf) {
        dim3 grid((N + 127) / 128, (M + 127) / 128);
        if (outbf) mfma_gemm<float, true><<<grid, 256, 0, stream>>>(A, WT, bias, C, M, N, K, accum);
        else       mfma_gemm<float, false><<<grid, 256, 0, stream>>>(A, WT, bias, C, M, N, K, accum);
    };
    auto gemm_b = [&](const u16* A, const u16* WT, const float* bias, void* C,
                      int M, int N, int K, int accum, bool outbf) {
        dim3 grid((N + 127) / 128, (M + 127) / 128);
        if (outbf) mfma_gemm<u16, true><<<grid, 256, 0, stream>>>(A, WT, bias, C, M, N, K, accum);
        else       mfma_gemm<u16, false><<<grid, 256, 0, stream>>>(A, WT, bias, C, M, N, K, accum);
    };
    auto gat_f32 = [&](const u16* T, const int* ptr, const int* idx, const float* inv,
                       float* out, int R, int accum) {
        gather_h_f32<<<(R + 3) / 4, 256, 0, stream>>>(T, ptr, idx, inv, out, R, accum);
    };
    auto gat_bf = [&](const u16* T, const int* ptr, const int* idx, const float* inv,
                      u16* out, int R, int accum) {
        gather_h_bf16<<<(R + 3) / 4, 256, 0, stream>>>(T, ptr, idx, inv, out, R, accum);
    };

    // ---- layer 0 (mean_agg(h)@W == mean_agg(h@W)) ----
    gemm_f(x_paper, wt_lin, lin_b, h_p_bf, P_NODES, H_CH, IN_CH, 0, true);      // h_p (bf16)
    gemm_b(h_p_bf, wt_r0p, r0p_b, out_p, P_NODES, H_CH, H_CH, 0, false);        // root paper (fp32)
    gemm_f(emb_a, wt_c0wr, nullptr, t0_bf, A_NODES, H_CH, H_CH, 0, true);       // emb@W_writes
    gat_f32(t0_bf, ptr_w, idx_w, inv_w, out_p, P_NODES, 1);
    gemm_b(h_p_bf, wt_c0ci, nullptr, t0_bf, P_NODES, H_CH, H_CH, 0, true);      // h_p@W_cites
    gat_f32(t0_bf, ptr_c, idx_c, inv_c, out_p, P_NODES, 1);
    gemm_f(emb_a, wt_r0a, r0a_b, out_a_bf, A_NODES, H_CH, H_CH, 0, true);       // root author (bf16)
    gemm_b(h_p_bf, wt_c0rv, nullptr, t0_bf, P_NODES, H_CH, H_CH, 0, true);      // h_p@W_revw
    gat_bf(t0_bf, ptr_r, idx_r, inv_r, out_a_bf, A_NODES, 1);

    relu_f32_to_bf16<<<(PH + 255) / 256, 256, 0, stream>>>(out_p, out_p_bf, PH);
    relu_bf16<<<(AH + 255) / 256, 256, 0, stream>>>(out_a_bf, AH);

    // ---- layer 1 ----
    gemm_b(out_p_bf, wt_r1, r1_b, logits, P_NODES, OUT_CH, H_CH, 0, false);     // root
    gemm_b(out_a_bf, wt_c1wr, nullptr, t_w_bf, A_NODES, OUT_CH, H_CH, 0, true); // h_a@W_writes
    gather_out_kernel<<<P_NODES, 256, 0, stream>>>(t_w_bf, ptr_w, idx_w, inv_w, logits, P_NODES);
    gat_bf(out_p_bf, ptr_c, idx_c, inv_c, agg_bf, P_NODES, 0);                  // mean_agg(h_p)
    gemm_b(agg_bf, wt_c1ci, nullptr, logits, P_NODES, OUT_CH, H_CH, 1, false);  // += agg@W_cites

    // ---- log_softmax in place ----
    log_softmax_kernel<<<P_NODES, 64, 0, stream>>>(logits, OUT_CH);
}

// Round 4
// 1469.012 us; speedup vs baseline: 4.7252x; 1.4043x over previous
//
#include <hip/hip_runtime.h>
#include <cstdint>
#include <cstddef>

// Problem constants (match reference)
#define P_NODES 100000
#define A_NODES 50000
#define IN_CH   128
#define H_CH    256
#define OUT_CH  349
#define NE_W    600000
#define NE_C    1000000

#define SCAN_BS 512

typedef unsigned short u16;
typedef unsigned int   u32;
typedef __bf16 bf16x8 __attribute__((ext_vector_type(8)));
typedef float  f32x4  __attribute__((ext_vector_type(4)));
typedef u16    u16x4  __attribute__((ext_vector_type(4)));
typedef u16    u16x8  __attribute__((ext_vector_type(8)));

// fp32 -> bf16 round-to-nearest-even
__device__ __forceinline__ u16 f2bf(float f) {
    u32 u = __builtin_bit_cast(u32, f);
    u += 0x7FFFu + ((u >> 16) & 1u);
    return (u16)(u >> 16);
}
__device__ __forceinline__ float bf2f(u16 v) {
    return __builtin_bit_cast(float, (u32)v << 16);
}

// ---------------------------------------------------------------------------
// MFMA bf16 GEMM: C[M,N] = A[M,K] @ W[K,N] + bias  (optional relu, bf16 out)
// A: row-major [M, lda] (fp32 or bf16).  WT: bf16 W^T, row-major [N, ldw].
// Tile 128x128, BK=32, 256 threads = 4 waves; wave owns a 64x64 quadrant
// (4x4 grid of 16x16x32 MFMA tiles). LDS rows padded to 40 bf16 (80 B).
// ---------------------------------------------------------------------------
#define SA 40

template<typename TA, bool OUTBF, bool RELU>
__global__ __launch_bounds__(256) void mfma_gemm(
    const TA* __restrict__ A, int lda,
    const u16* __restrict__ WT, int ldw,
    const float* __restrict__ bias, void* __restrict__ Cv, int ldc,
    int M, int N, int K)
{
    __shared__ u16 Asl[128 * SA];
    __shared__ u16 Bsl[128 * SA];

    const int tid  = threadIdx.x;
    const int blockM = blockIdx.y * 128;
    const int blockN = blockIdx.x * 128;

    const int w    = tid >> 6;         // wave 0..3
    const int lane = tid & 63;
    const int m16  = lane & 15;
    const int quad = lane >> 4;
    const int wr   = (w >> 1) * 64;    // wave quadrant row
    const int wc   = (w & 1) * 64;     // wave quadrant col

    f32x4 acc[4][4];
#pragma unroll
    for (int i = 0; i < 4; ++i)
#pragma unroll
        for (int j = 0; j < 4; ++j) acc[i][j] = (f32x4){0.f, 0.f, 0.f, 0.f};

    const int rs = tid >> 3;          // 0..31 (staging row within pass)
    const int kk = (tid & 7) * 4;     // 0..28 (staging k offset)

    for (int k0 = 0; k0 < K; k0 += 32) {
        // ---- stage A tile: 128 x 32 -> bf16 LDS ----
#pragma unroll
        for (int p = 0; p < 4; ++p) {
            int r  = p * 32 + rs;
            int gm = blockM + r;
            u16x4 o;
            if (gm < M) {
                if constexpr (sizeof(TA) == 4) {
                    const float4 v = *(const float4*)((const float*)A + (size_t)gm * lda + k0 + kk);
                    o[0] = f2bf(v.x); o[1] = f2bf(v.y); o[2] = f2bf(v.z); o[3] = f2bf(v.w);
                } else {
                    o = *(const u16x4*)((const u16*)A + (size_t)gm * lda + k0 + kk);
                }
            } else {
                o = (u16x4){0, 0, 0, 0};
            }
            *(u16x4*)&Asl[r * SA + kk] = o;
        }
        // ---- stage B tile from WT[N][ldw] ----
#pragma unroll
        for (int p = 0; p < 4; ++p) {
            int n  = p * 32 + rs;
            int gn = blockN + n;
            u16x4 o;
            if (gn < N) o = *(const u16x4*)(WT + (size_t)gn * ldw + k0 + kk);
            else        o = (u16x4){0, 0, 0, 0};
            *(u16x4*)&Bsl[n * SA + kk] = o;
        }
        __syncthreads();

        // ---- fragments + MFMA ----
        bf16x8 af[4], bf[4];
#pragma unroll
        for (int mt = 0; mt < 4; ++mt) {
            int off = (wr + mt * 16 + m16) * SA + quad * 8;
            u16x4 a0 = *(const u16x4*)&Asl[off];
            u16x4 a1 = *(const u16x4*)&Asl[off + 4];
            u16x8 av = {a0[0], a0[1], a0[2], a0[3], a1[0], a1[1], a1[2], a1[3]};
            af[mt] = __builtin_bit_cast(bf16x8, av);
        }
#pragma unroll
        for (int nt = 0; nt < 4; ++nt) {
            int off = (wc + nt * 16 + m16) * SA + quad * 8;
            u16x4 b0 = *(const u16x4*)&Bsl[off];
            u16x4 b1 = *(const u16x4*)&Bsl[off + 4];
            u16x8 bv = {b0[0], b0[1], b0[2], b0[3], b1[0], b1[1], b1[2], b1[3]};
            bf[nt] = __builtin_bit_cast(bf16x8, bv);
        }
#pragma unroll
        for (int mt = 0; mt < 4; ++mt)
#pragma unroll
            for (int nt = 0; nt < 4; ++nt)
                acc[mt][nt] = __builtin_amdgcn_mfma_f32_16x16x32_bf16(
                    af[mt], bf[nt], acc[mt][nt], 0, 0, 0);
        __syncthreads();
    }

    // ---- epilogue: C/D layout col=lane&15, row=quad*4+reg ----
#pragma unroll
    for (int mt = 0; mt < 4; ++mt) {
#pragma unroll
        for (int nt = 0; nt < 4; ++nt) {
            int col = blockN + wc + nt * 16 + m16;
            if (col >= N) continue;
#pragma unroll
            for (int reg = 0; reg < 4; ++reg) {
                int row = blockM + wr + mt * 16 + quad * 4 + reg;
                if (row >= M) continue;
                float v = acc[mt][nt][reg];
                if (bias) v += bias[col];
                if constexpr (RELU) v = fmaxf(v, 0.f);
                size_t off = (size_t)row * ldc + col;
                if constexpr (OUTBF) ((u16*)Cv)[off] = f2bf(v);
                else                 ((float*)Cv)[off] = v;
            }
        }
    }
}

// ---------------------------------------------------------------------------
// Weight transpose + bf16 convert into stacked W^T: W[K,N] fp32 ->
// WT[n * ldk + koff + k] bf16
// ---------------------------------------------------------------------------
__global__ void transpose_w_kernel(const float* __restrict__ W, u16* __restrict__ WT,
                                   int K, int N, int ldk, int koff)
{
    int i = blockIdx.x * blockDim.x + threadIdx.x;
    if (i < K * N) {
        int k = i / N, n = i - k * N;
        WT[(size_t)n * ldk + koff + k] = f2bf(W[i]);
    }
}

// emb fp32 [A,256] -> bf16 with row stride ldo
__global__ void emb_to_bf16(const float* __restrict__ x, u16* __restrict__ y, int ldo)
{
    int i = blockIdx.x * blockDim.x + threadIdx.x;   // one float4 per thread
    if (i < A_NODES * H_CH / 4) {
        int r = i >> 6, c = (i & 63) * 4;
        float4 v = *(const float4*)(x + (size_t)r * H_CH + c);
        u16x4 o = {f2bf(v.x), f2bf(v.y), f2bf(v.z), f2bf(v.w)};
        *(u16x4*)(y + (size_t)r * ldo + c) = o;
    }
}

// ---------------------------------------------------------------------------
// CSR construction: degree count -> exclusive scan -> bucket fill
// ---------------------------------------------------------------------------
__global__ void deg_kernel(const int* __restrict__ dst, int* __restrict__ deg, int E)
{
    int e = blockIdx.x * blockDim.x + threadIdx.x;
    if (e < E) atomicAdd(&deg[dst[e]], 1);
}

__global__ __launch_bounds__(SCAN_BS) void scan_phase_a(
    const int* __restrict__ deg, int* __restrict__ ptr, int* __restrict__ blksum, int n)
{
    __shared__ int s[SCAN_BS];
    int tid = threadIdx.x;
    int i = blockIdx.x * SCAN_BS + tid;
    int v = (i < n) ? deg[i] : 0;
    s[tid] = v;
    __syncthreads();
    for (int off = 1; off < SCAN_BS; off <<= 1) {
        int t = 0;
        if (tid >= off) t = s[tid - off];
        __syncthreads();
        s[tid] += t;
        __syncthreads();
    }
    if (i < n) ptr[i] = s[tid] - v;
    if (tid == SCAN_BS - 1) blksum[blockIdx.x] = s[tid];
}

__global__ __launch_bounds__(SCAN_BS) void scan_phase_b(int* __restrict__ blksum, int nb)
{
    __shared__ int s[SCAN_BS];
    int tid = threadIdx.x;
    int v = (tid < nb) ? blksum[tid] : 0;
    s[tid] = v;
    __syncthreads();
    for (int off = 1; off < SCAN_BS; off <<= 1) {
        int t = 0;
        if (tid >= off) t = s[tid - off];
        __syncthreads();
        s[tid] += t;
        __syncthreads();
    }
    if (tid < nb) blksum[tid] = s[tid] - v;
}

__global__ void scan_phase_c(const int* __restrict__ deg, int* __restrict__ ptr,
                             const int* __restrict__ blkoff, int* __restrict__ cur,
                             float* __restrict__ inv, int n, int E)
{
    int i = blockIdx.x * blockDim.x + threadIdx.x;
    if (i < n) {
        int p = ptr[i] + blkoff[i / SCAN_BS];
        ptr[i] = p;
        cur[i] = p;
        inv[i] = 1.0f / fmaxf((float)deg[i], 1.0f);
    }
    if (i == 0) ptr[n] = E;
}

__global__ void fill_kernel(const int* __restrict__ src, const int* __restrict__ dst,
                            int* __restrict__ cur, int* __restrict__ idx, int E)
{
    int e = blockIdx.x * blockDim.x + threadIdx.x;
    if (e < E) {
        int pos = atomicAdd(&cur[dst[e]], 1);
        idx[pos] = src[e];
    }
}

// ---------------------------------------------------------------------------
// Gather aggregation, D=256 bf16. Half-wave (32 lanes x 16B) per dst row,
// 2-edge unroll for MLP. out[row] = mean over in-edges of T[idx].
// ---------------------------------------------------------------------------
__global__ __launch_bounds__(256) void gather_bf16(
    const u16* __restrict__ T, int ldt,
    const int* __restrict__ ptr, const int* __restrict__ idx,
    const float* __restrict__ inv, u16* __restrict__ out, int ldo, int R)
{
    int row = blockIdx.x * 8 + (threadIdx.x >> 5);
    if (row >= R) return;
    int l = (threadIdx.x & 31) * 8;   // element offset, 16B per lane
    int s = ptr[row], e = ptr[row + 1];
    float acc[8];
#pragma unroll
    for (int q = 0; q < 8; ++q) acc[q] = 0.f;
    int j = s;
    for (; j + 1 < e; j += 2) {
        int i0 = idx[j], i1 = idx[j + 1];
        u16x8 t0 = *(const u16x8*)(T + (size_t)i0 * ldt + l);
        u16x8 t1 = *(const u16x8*)(T + (size_t)i1 * ldt + l);
#pragma unroll
        for (int q = 0; q < 8; ++q) acc[q] += bf2f(t0[q]) + bf2f(t1[q]);
    }
    if (j < e) {
        int i0 = idx[j];
        u16x8 t0 = *(const u16x8*)(T + (size_t)i0 * ldt + l);
#pragma unroll
        for (int q = 0; q < 8; ++q) acc[q] += bf2f(t0[q]);
    }
    float wgt = inv[row];
    u16x8 o;
#pragma unroll
    for (int q = 0; q < 8; ++q) o[q] = f2bf(acc[q] * wgt);
    *(u16x8*)(out + (size_t)row * ldo + l) = o;
}

// In-place per-row log_softmax, one wave per row, register-resident (349<=384)
__global__ __launch_bounds__(64) void log_softmax_kernel(float* __restrict__ x)
{
    const int row = blockIdx.x;
    const int lane = threadIdx.x;
    float* xr = x + (size_t)row * OUT_CH;

    float v[6];
    float m = -3.402823466e38f;
#pragma unroll
    for (int o = 0; o < 6; ++o) {
        int j = lane + o * 64;
        v[o] = (j < OUT_CH) ? xr[j] : -3.402823466e38f;
        m = fmaxf(m, v[o]);
    }
#pragma unroll
    for (int off = 32; off > 0; off >>= 1) m = fmaxf(m, __shfl_xor(m, off));

    float s = 0.f;
#pragma unroll
    for (int o = 0; o < 6; ++o) {
        int j = lane + o * 64;
        if (j < OUT_CH) s += __expf(v[o] - m);
    }
#pragma unroll
    for (int off = 32; off > 0; off >>= 1) s += __shfl_xor(s, off);

    float lse = m + __logf(s);
#pragma unroll
    for (int o = 0; o < 6; ++o) {
        int j = lane + o * 64;
        if (j < OUT_CH) xr[j] = v[o] - lse;
    }
}

// ---------------------------------------------------------------------------
extern "C" void kernel_launch(void* const* d_in, const int* in_sizes, int n_in,
                              void* d_out, int out_size, void* d_ws, size_t ws_size,
                              hipStream_t stream)
{
    const float* x_paper = (const float*)d_in[0];
    const float* emb_a   = (const float*)d_in[1];
    const float* lin_w   = (const float*)d_in[2];
    const float* lin_b   = (const float*)d_in[3];
    const float* r0p_w   = (const float*)d_in[4];
    const float* r0p_b   = (const float*)d_in[5];
    const float* r0a_w   = (const float*)d_in[6];
    const float* r0a_b   = (const float*)d_in[7];
    const float* c0_wr   = (const float*)d_in[8];
    const float* c0_ci   = (const float*)d_in[9];
    const float* c0_rv   = (const float*)d_in[10];
    const float* r1_w    = (const float*)d_in[11];
    const float* r1_b    = (const float*)d_in[12];
    const float* c1_wr   = (const float*)d_in[13];
    const float* c1_ci   = (const float*)d_in[14];
    const int*   w_src   = (const int*)d_in[15];
    const int*   w_dst   = (const int*)d_in[16];
    const int*   c_src   = (const int*)d_in[17];
    const int*   c_dst   = (const int*)d_in[18];
    const int*   r_src   = (const int*)d_in[19];
    const int*   r_dst   = (const int*)d_in[20];

    // ---------------- workspace layout (d_ws) ----------------
    const size_t P768 = (size_t)P_NODES * 768;

    u16* big_A0 = (u16*)d_ws;              // P x 768: [h_p | agg_w0 | agg_c0]
    u16* big_A1 = big_A0 + P768;           // P x 768: [relu_p | agg_w1 | agg_c1]
    u16* wt_lin = big_A1 + P768;           // 256 x 128
    u16* wt_l0p = wt_lin + 256 * 128;      // 256 x 768  [r0p; c0wr; c0ci]^T
    u16* wt_l0a = wt_l0p + 256 * 768;      // 256 x 512  [r0a; c0rv]^T
    u16* wt_l1  = wt_l0a + 256 * 512;      // 349 x 768  [r1; c1wr; c1ci]^T
    float* inv_w = (float*)(wt_l1 + 349 * 768 + 64);
    float* inv_c = inv_w + P_NODES;
    float* inv_r = inv_c + P_NODES;

    int* ip    = (int*)(inv_r + A_NODES);
    int* deg_w = ip;                 ip += P_NODES;
    int* deg_c = ip;                 ip += P_NODES;
    int* deg_r = ip;                 ip += A_NODES;
    int* ptr_w = ip;                 ip += P_NODES + 1;
    int* ptr_c = ip;                 ip += P_NODES + 1;
    int* ptr_r = ip;                 ip += A_NODES + 1;
    int* cur_w = ip;                 ip += P_NODES;
    int* cur_c = ip;                 ip += P_NODES;
    int* cur_r = ip;                 ip += A_NODES;
    int* idx_w = ip;                 ip += NE_W;
    int* idx_c = ip;                 ip += NE_C;
    int* idx_r = ip;                 ip += NE_W;
    int* blk   = ip;                 ip += 1024;

    // ---------------- d_out-resident scratch (dead before final GEMM) ------
    u16* big_A0a  = (u16*)d_out;                         // A x 512: [emb_bf | agg_r0]
    u16* out_a_bf = big_A0a + (size_t)A_NODES * 512;     // A x 256
    float* logits = (float*)d_out;                       // P x 349 (final)

    // ---------------- weight transposes into stacked W^T ----------------
    auto twp = [&](const float* W, u16* WT, int K, int N, int ldk, int koff) {
        transpose_w_kernel<<<(K * N + 255) / 256, 256, 0, stream>>>(W, WT, K, N, ldk, koff);
    };
    twp(lin_w, wt_lin, IN_CH, H_CH, 128, 0);
    twp(r0p_w, wt_l0p, H_CH, H_CH, 768, 0);
    twp(c0_wr, wt_l0p, H_CH, H_CH, 768, 256);
    twp(c0_ci, wt_l0p, H_CH, H_CH, 768, 512);
    twp(r0a_w, wt_l0a, H_CH, H_CH, 512, 0);
    twp(c0_rv, wt_l0a, H_CH, H_CH, 512, 256);
    twp(r1_w,  wt_l1,  H_CH, OUT_CH, 768, 0);
    twp(c1_wr, wt_l1,  H_CH, OUT_CH, 768, 256);
    twp(c1_ci, wt_l1,  H_CH, OUT_CH, 768, 512);

    emb_to_bf16<<<(A_NODES * H_CH / 4 + 255) / 256, 256, 0, stream>>>(emb_a, big_A0a, 512);

    // ---------------- CSR builds ----------------
    hipMemsetAsync(deg_w, 0, (size_t)(2 * P_NODES + A_NODES) * sizeof(int), stream);
    deg_kernel<<<(NE_W + 255) / 256, 256, 0, stream>>>(w_dst, deg_w, NE_W);
    deg_kernel<<<(NE_C + 255) / 256, 256, 0, stream>>>(c_dst, deg_c, NE_C);
    deg_kernel<<<(NE_W + 255) / 256, 256, 0, stream>>>(r_dst, deg_r, NE_W);

    auto build_csr = [&](const int* src, const int* dst, int* deg, int* ptr, int* cur,
                         int* idx, float* inv, int n, int E) {
        int nb = (n + SCAN_BS - 1) / SCAN_BS;
        scan_phase_a<<<nb, SCAN_BS, 0, stream>>>(deg, ptr, blk, n);
        scan_phase_b<<<1, SCAN_BS, 0, stream>>>(blk, nb);
        scan_phase_c<<<(n + 255) / 256, 256, 0, stream>>>(deg, ptr, blk, cur, inv, n, E);
        fill_kernel<<<(E + 255) / 256, 256, 0, stream>>>(src, dst, cur, idx, E);
    };
    build_csr(w_src, w_dst, deg_w, ptr_w, cur_w, idx_w, inv_w, P_NODES, NE_W);
    build_csr(c_src, c_dst, deg_c, ptr_c, cur_c, idx_c, inv_c, P_NODES, NE_C);
    build_csr(r_src, r_dst, deg_r, ptr_r, cur_r, idx_r, inv_r, A_NODES, NE_W);

    // ---------------- fused pipeline ----------------
    auto gat = [&](const u16* T, int ldt, const int* ptr, const int* idx,
                   const float* inv, u16* out, int ldo, int R) {
        gather_bf16<<<(R + 7) / 8, 256, 0, stream>>>(T, ldt, ptr, idx, inv, out, ldo, R);
    };

    // h_p = x_paper @ lin_w + b  -> big_A0 cols [0:256)
    {
        dim3 grid((H_CH + 127) / 128, (P_NODES + 127) / 128);
        mfma_gemm<float, true, false><<<grid, 256, 0, stream>>>(
            x_paper, IN_CH, wt_lin, 128, lin_b, big_A0, 768, P_NODES, H_CH, IN_CH);
    }
    // agg_w0 = mean_w(emb)   -> big_A0 cols [256:512)
    gat(big_A0a, 512, ptr_w, idx_w, inv_w, big_A0 + 256, 768, P_NODES);
    // agg_c0 = mean_c(h_p)   -> big_A0 cols [512:768)
    gat(big_A0, 768, ptr_c, idx_c, inv_c, big_A0 + 512, 768, P_NODES);
    // agg_r0 = mean_r(h_p)   -> big_A0a cols [256:512)
    gat(big_A0, 768, ptr_r, idx_r, inv_r, big_A0a + 256, 512, A_NODES);

    // relu_p = relu(big_A0 @ [r0p; c0wr; c0ci] + b) -> big_A1 cols [0:256)
    {
        dim3 grid((H_CH + 127) / 128, (P_NODES + 127) / 128);
        mfma_gemm<u16, true, true><<<grid, 256, 0, stream>>>(
            big_A0, 768, wt_l0p, 768, r0p_b, big_A1, 768, P_NODES, H_CH, 768);
    }
    // relu_a = relu(big_A0a @ [r0a; c0rv] + b) -> out_a_bf
    {
        dim3 grid((H_CH + 127) / 128, (A_NODES + 127) / 128);
        mfma_gemm<u16, true, true><<<grid, 256, 0, stream>>>(
            big_A0a, 512, wt_l0a, 512, r0a_b, out_a_bf, 256, A_NODES, H_CH, 512);
    }
    // agg_w1 = mean_w(relu_a) -> big_A1 cols [256:512)
    gat(out_a_bf, 256, ptr_w, idx_w, inv_w, big_A1 + 256, 768, P_NODES);
    // agg_c1 = mean_c(relu_p) -> big_A1 cols [512:768)
    gat(big_A1, 768, ptr_c, idx_c, inv_c, big_A1 + 512, 768, P_NODES);

    // logits = big_A1 @ [r1; c1wr; c1ci] + b  (fp32, overwrites d_out scratch)
    {
        dim3 grid((OUT_CH + 127) / 128, (P_NODES + 127) / 128);
        mfma_gemm<u16, false, false><<<grid, 256, 0, stream>>>(
            big_A1, 768, wt_l1, 768, r1_b, logits, OUT_CH, P_NODES, OUT_CH, 768);
    }

    // ---------------- log_softmax in place ----------------
    log_softmax_kernel<<<P_NODES, 64, 0, stream>>>(logits);
}

// Round 5
// 1196.447 us; speedup vs baseline: 5.8017x; 1.2278x over previous
//
#include <hip/hip_runtime.h>
#include <cstdint>
#include <cstddef>

// Problem constants (match reference)
#define P_NODES 100000
#define A_NODES 50000
#define IN_CH   128
#define H_CH    256
#define OUT_CH  349
#define NE_W    600000
#define NE_C    1000000

#define SCAN_BS 512

typedef unsigned short u16;
typedef unsigned int   u32;
typedef __bf16 bf16x8 __attribute__((ext_vector_type(8)));
typedef float  f32x4  __attribute__((ext_vector_type(4)));
typedef u16    u16x4  __attribute__((ext_vector_type(4)));
typedef u16    u16x8  __attribute__((ext_vector_type(8)));

// fp32 -> bf16 round-to-nearest-even
__device__ __forceinline__ u16 f2bf(float f) {
    u32 u = __builtin_bit_cast(u32, f);
    u += 0x7FFFu + ((u >> 16) & 1u);
    return (u16)(u >> 16);
}
__device__ __forceinline__ float bf2f(u16 v) {
    return __builtin_bit_cast(float, (u32)v << 16);
}

// async global->LDS, 16 B per lane. LDS dest is wave-uniform base + lane*16.
typedef const __attribute__((address_space(1))) u32 gas_u32;
typedef __attribute__((address_space(3))) u32 las_u32;
__device__ __forceinline__ void gl_lds16(const void* g, void* l)
{
    __builtin_amdgcn_global_load_lds(
        reinterpret_cast<gas_u32*>(reinterpret_cast<uintptr_t>(g)),
        reinterpret_cast<las_u32*>(reinterpret_cast<uintptr_t>(l)),
        16, 0, 0);
}

// ---------------------------------------------------------------------------
// MFMA bf16 GEMM, m97 structure: C[M,N] = A[M,K] @ W[K,N] + bias
// A: bf16 row-major [M,lda]. WT: bf16 W^T row-major [N,ldw]. K % 32 == 0.
// Tile 128x128, BK=32, 256 thr = 4 waves, each wave a 64x64 quadrant of
// 4x4 16x16x32 MFMA tiles. Staging via global_load_lds(16B); LDS unpadded
// (row = 32 u16 = 64 B) with XOR swizzle chunk ^= (row>>1)&3 applied on the
// global-address side so fragment ds_read_b128s are 2-way (free).
// ---------------------------------------------------------------------------
template<bool OUTBF, bool RELU>
__global__ __launch_bounds__(256) void mfma_gemm(
    const u16* __restrict__ A, int lda,
    const u16* __restrict__ WT, int ldw,
    const float* __restrict__ bias, void* __restrict__ Cv, int ldc,
    int M, int N, int K)
{
    __shared__ u16 Asl[128 * 32];
    __shared__ u16 Bsl[128 * 32];

    const int tid = threadIdx.x;
    const int blockM = blockIdx.y * 128;
    const int blockN = blockIdx.x * 128;
    const int w    = tid >> 6;
    const int lane = tid & 63;
    const int m16  = lane & 15;
    const int quad = lane >> 4;
    const int wr   = (w >> 1) * 64;
    const int wc   = (w & 1) * 64;

    // ragged blocks: pre-zero LDS; masked DMA lanes never overwrite -> zeros
    if (blockM + 128 > M || blockN + 128 > N) {
        for (int i = tid; i < 128 * 32; i += 256) { Asl[i] = 0; Bsl[i] = 0; }
    }
    __syncthreads();

    // staging: wave w covers tile rows [w*32, w*32+32) in two 16-row halves
    const int ra  = lane >> 2;               // 0..15 row within half
    const int rA0 = w * 32 + ra;             // tile row, half 0
    const int rA1 = rA0 + 16;                // half 1 (same swizzle: +16 keeps (r>>1)&3)
    const int cs  = ((lane & 3) ^ ((rA0 >> 1) & 3)) * 8;  // swizzled k-offset (u16)

    const u16* gA0 = A  + (size_t)(blockM + rA0) * lda + cs;
    const u16* gA1 = A  + (size_t)(blockM + rA1) * lda + cs;
    const u16* gB0 = WT + (size_t)(blockN + rA0) * ldw + cs;
    const u16* gB1 = WT + (size_t)(blockN + rA1) * ldw + cs;
    u16* lA0 = &Asl[(w * 32) * 32];
    u16* lA1 = &Asl[(w * 32 + 16) * 32];
    u16* lB0 = &Bsl[(w * 32) * 32];
    u16* lB1 = &Bsl[(w * 32 + 16) * 32];
    const bool vA0 = blockM + rA0 < M, vA1 = blockM + rA1 < M;
    const bool vB0 = blockN + rA0 < N, vB1 = blockN + rA1 < N;

    // fragment read swizzle (row-in-tile = 16*t + m16 -> s = (m16>>1)&3)
    const int swz = (quad ^ ((m16 >> 1) & 3)) * 8;

    f32x4 acc[4][4];
#pragma unroll
    for (int i = 0; i < 4; ++i)
#pragma unroll
        for (int j = 0; j < 4; ++j) acc[i][j] = (f32x4){0.f, 0.f, 0.f, 0.f};

    for (int k0 = 0; k0 < K; k0 += 32) {
        if (vA0) gl_lds16(gA0 + k0, lA0);
        if (vA1) gl_lds16(gA1 + k0, lA1);
        if (vB0) gl_lds16(gB0 + k0, lB0);
        if (vB1) gl_lds16(gB1 + k0, lB1);
        __syncthreads();

        bf16x8 af[4], bfr[4];
#pragma unroll
        for (int mt = 0; mt < 4; ++mt)
            af[mt] = *(const bf16x8*)&Asl[(wr + mt * 16 + m16) * 32 + swz];
#pragma unroll
        for (int nt = 0; nt < 4; ++nt)
            bfr[nt] = *(const bf16x8*)&Bsl[(wc + nt * 16 + m16) * 32 + swz];
#pragma unroll
        for (int mt = 0; mt < 4; ++mt)
#pragma unroll
            for (int nt = 0; nt < 4; ++nt)
                acc[mt][nt] = __builtin_amdgcn_mfma_f32_16x16x32_bf16(
                    af[mt], bfr[nt], acc[mt][nt], 0, 0, 0);
        __syncthreads();
    }

    // epilogue: C/D layout col=lane&15, row=quad*4+reg
#pragma unroll
    for (int mt = 0; mt < 4; ++mt) {
#pragma unroll
        for (int nt = 0; nt < 4; ++nt) {
            int col = blockN + wc + nt * 16 + m16;
            if (col >= N) continue;
#pragma unroll
            for (int reg = 0; reg < 4; ++reg) {
                int row = blockM + wr + mt * 16 + quad * 4 + reg;
                if (row >= M) continue;
                float v = acc[mt][nt][reg];
                if (bias) v += bias[col];
                if constexpr (RELU) v = fmaxf(v, 0.f);
                size_t off = (size_t)row * ldc + col;
                if constexpr (OUTBF) ((u16*)Cv)[off] = f2bf(v);
                else                 ((float*)Cv)[off] = v;
            }
        }
    }
}

// ---------------------------------------------------------------------------
// Fused input converts: x_paper -> bf16 [P,128]; emb -> bf16 [A,512-stride]
// ---------------------------------------------------------------------------
__global__ void prep_convert(const float* __restrict__ x, u16* __restrict__ x_bf,
                             const float* __restrict__ emb, u16* __restrict__ emb_bf)
{
    int i = blockIdx.x * blockDim.x + threadIdx.x;
    const int NX = P_NODES * IN_CH / 4;
    const int NE = A_NODES * H_CH / 4;
    if (i < NX) {
        float4 v = *(const float4*)(x + (size_t)i * 4);
        u16x4 o = {f2bf(v.x), f2bf(v.y), f2bf(v.z), f2bf(v.w)};
        *(u16x4*)(x_bf + (size_t)i * 4) = o;
    } else if (i < NX + NE) {
        int j = i - NX;
        int r = j >> 6, c = (j & 63) * 4;
        float4 v = *(const float4*)(emb + (size_t)r * H_CH + c);
        u16x4 o = {f2bf(v.x), f2bf(v.y), f2bf(v.z), f2bf(v.w)};
        *(u16x4*)(emb_bf + (size_t)r * 512 + c) = o;
    }
}

// ---------------------------------------------------------------------------
// All 9 weight transposes (fp32 W[K,N] -> bf16 WT[n*ldk + koff + k]) fused.
// ---------------------------------------------------------------------------
__global__ void transpose_all(
    const float* __restrict__ lin, const float* __restrict__ r0p,
    const float* __restrict__ c0wr, const float* __restrict__ c0ci,
    const float* __restrict__ r0a, const float* __restrict__ c0rv,
    const float* __restrict__ r1, const float* __restrict__ c1wr,
    const float* __restrict__ c1ci,
    u16* __restrict__ wt_lin, u16* __restrict__ wt_l0p,
    u16* __restrict__ wt_l0a, u16* __restrict__ wt_l1)
{
    int i = blockIdx.x * blockDim.x + threadIdx.x;
    const float* W; u16* WT; int N, ldk, koff;
    if (i < 32768)       { W = lin;  WT = wt_lin; N = 256; ldk = 128; koff = 0;   }
    else if (i < 98304)  { i -= 32768;  W = r0p;  WT = wt_l0p; N = 256; ldk = 768; koff = 0;   }
    else if (i < 163840) { i -= 98304;  W = c0wr; WT = wt_l0p; N = 256; ldk = 768; koff = 256; }
    else if (i < 229376) { i -= 163840; W = c0ci; WT = wt_l0p; N = 256; ldk = 768; koff = 512; }
    else if (i < 294912) { i -= 229376; W = r0a;  WT = wt_l0a; N = 256; ldk = 512; koff = 0;   }
    else if (i < 360448) { i -= 294912; W = c0rv; WT = wt_l0a; N = 256; ldk = 512; koff = 256; }
    else if (i < 449792) { i -= 360448; W = r1;   WT = wt_l1;  N = 349; ldk = 768; koff = 0;   }
    else if (i < 539136) { i -= 449792; W = c1wr; WT = wt_l1;  N = 349; ldk = 768; koff = 256; }
    else if (i < 628480) { i -= 539136; W = c1ci; WT = wt_l1;  N = 349; ldk = 768; koff = 512; }
    else return;
    int k = i / N, n = i - k * N;
    WT[(size_t)n * ldk + koff + k] = f2bf(W[(size_t)k * N + n]);
}

// ---------------------------------------------------------------------------
// CSR construction (3 graphs fused per phase)
// ---------------------------------------------------------------------------
__global__ void deg3_kernel(const int* __restrict__ wd, const int* __restrict__ cd,
                            const int* __restrict__ rd,
                            int* __restrict__ deg_w, int* __restrict__ deg_c,
                            int* __restrict__ deg_r)
{
    int e = blockIdx.x * blockDim.x + threadIdx.x;
    if (e < NE_W) atomicAdd(&deg_w[wd[e]], 1);
    if (e < NE_C) atomicAdd(&deg_c[cd[e]], 1);
    if (e < NE_W) atomicAdd(&deg_r[rd[e]], 1);
}

__global__ __launch_bounds__(SCAN_BS) void scan_a3(
    const int* __restrict__ dw, const int* __restrict__ dc, const int* __restrict__ dr,
    int* __restrict__ pw, int* __restrict__ pc, int* __restrict__ pr, int* __restrict__ blk)
{
    __shared__ int s[SCAN_BS];
    int g = blockIdx.y;
    const int* deg = (g == 0) ? dw : (g == 1) ? dc : dr;
    int* ptr = (g == 0) ? pw : (g == 1) ? pc : pr;
    int n = (g == 2) ? A_NODES : P_NODES;
    int tid = threadIdx.x;
    int i = blockIdx.x * SCAN_BS + tid;
    int v = (i < n) ? deg[i] : 0;
    s[tid] = v;
    __syncthreads();
    for (int off = 1; off < SCAN_BS; off <<= 1) {
        int t = 0;
        if (tid >= off) t = s[tid - off];
        __syncthreads();
        s[tid] += t;
        __syncthreads();
    }
    if (i < n) ptr[i] = s[tid] - v;
    if (tid == SCAN_BS - 1) blk[g * 256 + blockIdx.x] = s[tid];
}

__global__ __launch_bounds__(SCAN_BS) void scan_b3(int* __restrict__ blk)
{
    __shared__ int s[SCAN_BS];
    int g = blockIdx.x;
    int tid = threadIdx.x;
    int v = (tid < 256) ? blk[g * 256 + tid] : 0;
    s[tid] = v;
    __syncthreads();
    for (int off = 1; off < SCAN_BS; off <<= 1) {
        int t = 0;
        if (tid >= off) t = s[tid - off];
        __syncthreads();
        s[tid] += t;
        __syncthreads();
    }
    if (tid < 256) blk[g * 256 + tid] = s[tid] - v;
}

__global__ void scan_c3(const int* __restrict__ dw, const int* __restrict__ dc,
                        const int* __restrict__ dr,
                        int* __restrict__ pw, int* __restrict__ pc, int* __restrict__ pr,
                        const int* __restrict__ blk,
                        int* __restrict__ cw, int* __restrict__ cc, int* __restrict__ cr,
                        float* __restrict__ iw, float* __restrict__ ic, float* __restrict__ ir)
{
    int g = blockIdx.y;
    const int* deg = (g == 0) ? dw : (g == 1) ? dc : dr;
    int* ptr = (g == 0) ? pw : (g == 1) ? pc : pr;
    int* cur = (g == 0) ? cw : (g == 1) ? cc : cr;
    float* inv = (g == 0) ? iw : (g == 1) ? ic : ir;
    int n = (g == 2) ? A_NODES : P_NODES;
    int E = (g == 1) ? NE_C : NE_W;
    int i = blockIdx.x * blockDim.x + threadIdx.x;
    if (i < n) {
        int p = ptr[i] + blk[g * 256 + i / SCAN_BS];
        ptr[i] = p;
        cur[i] = p;
        inv[i] = 1.0f / fmaxf((float)deg[i], 1.0f);
    }
    if (i == 0) ptr[n] = E;
}

__global__ void fill3_kernel(
    const int* __restrict__ wsrc, const int* __restrict__ wdst,
    const int* __restrict__ csrc, const int* __restrict__ cdst,
    const int* __restrict__ rsrc, const int* __restrict__ rdst,
    int* __restrict__ cw, int* __restrict__ cc, int* __restrict__ cr,
    int* __restrict__ iw, int* __restrict__ ic, int* __restrict__ ir)
{
    int e = blockIdx.x * blockDim.x + threadIdx.x;
    if (e < NE_W) { int p = atomicAdd(&cw[wdst[e]], 1); iw[p] = wsrc[e]; }
    if (e < NE_C) { int p = atomicAdd(&cc[cdst[e]], 1); ic[p] = csrc[e]; }
    if (e < NE_W) { int p = atomicAdd(&cr[rdst[e]], 1); ir[p] = rsrc[e]; }
}

// ---------------------------------------------------------------------------
// Gather aggregation, D=256 bf16. Half-wave (32 lanes x 16B) per dst row,
// 4-edge unroll (8 row-loads in flight per wave).
// ---------------------------------------------------------------------------
__global__ __launch_bounds__(256) void gather_bf16(
    const u16* __restrict__ T, int ldt,
    const int* __restrict__ ptr, const int* __restrict__ idx,
    const float* __restrict__ inv, u16* __restrict__ out, int ldo, int R)
{
    int row = blockIdx.x * 8 + (threadIdx.x >> 5);
    if (row >= R) return;
    int l = (threadIdx.x & 31) * 8;
    int s = ptr[row], e = ptr[row + 1];
    float acc[8];
#pragma unroll
    for (int q = 0; q < 8; ++q) acc[q] = 0.f;
    int j = s;
    for (; j + 3 < e; j += 4) {
        int i0 = idx[j], i1 = idx[j + 1], i2 = idx[j + 2], i3 = idx[j + 3];
        u16x8 t0 = *(const u16x8*)(T + (size_t)i0 * ldt + l);
        u16x8 t1 = *(const u16x8*)(T + (size_t)i1 * ldt + l);
        u16x8 t2 = *(const u16x8*)(T + (size_t)i2 * ldt + l);
        u16x8 t3 = *(const u16x8*)(T + (size_t)i3 * ldt + l);
#pragma unroll
        for (int q = 0; q < 8; ++q)
            acc[q] += (bf2f(t0[q]) + bf2f(t1[q])) + (bf2f(t2[q]) + bf2f(t3[q]));
    }
    for (; j < e; ++j) {
        int i0 = idx[j];
        u16x8 t0 = *(const u16x8*)(T + (size_t)i0 * ldt + l);
#pragma unroll
        for (int q = 0; q < 8; ++q) acc[q] += bf2f(t0[q]);
    }
    float wgt = inv[row];
    u16x8 o;
#pragma unroll
    for (int q = 0; q < 8; ++q) o[q] = f2bf(acc[q] * wgt);
    *(u16x8*)(out + (size_t)row * ldo + l) = o;
}

// In-place per-row log_softmax, one wave per row, register-resident
__global__ __launch_bounds__(64) void log_softmax_kernel(float* __restrict__ x)
{
    const int row = blockIdx.x;
    const int lane = threadIdx.x;
    float* xr = x + (size_t)row * OUT_CH;

    float v[6];
    float m = -3.402823466e38f;
#pragma unroll
    for (int o = 0; o < 6; ++o) {
        int j = lane + o * 64;
        v[o] = (j < OUT_CH) ? xr[j] : -3.402823466e38f;
        m = fmaxf(m, v[o]);
    }
#pragma unroll
    for (int off = 32; off > 0; off >>= 1) m = fmaxf(m, __shfl_xor(m, off));

    float s = 0.f;
#pragma unroll
    for (int o = 0; o < 6; ++o) {
        int j = lane + o * 64;
        if (j < OUT_CH) s += __expf(v[o] - m);
    }
#pragma unroll
    for (int off = 32; off > 0; off >>= 1) s += __shfl_xor(s, off);

    float lse = m + __logf(s);
#pragma unroll
    for (int o = 0; o < 6; ++o) {
        int j = lane + o * 64;
        if (j < OUT_CH) xr[j] = v[o] - lse;
    }
}

// ---------------------------------------------------------------------------
extern "C" void kernel_launch(void* const* d_in, const int* in_sizes, int n_in,
                              void* d_out, int out_size, void* d_ws, size_t ws_size,
                              hipStream_t stream)
{
    const float* x_paper = (const float*)d_in[0];
    const float* emb_a   = (const float*)d_in[1];
    const float* lin_w   = (const float*)d_in[2];
    const float* lin_b   = (const float*)d_in[3];
    const float* r0p_w   = (const float*)d_in[4];
    const float* r0p_b   = (const float*)d_in[5];
    const float* r0a_w   = (const float*)d_in[6];
    const float* r0a_b   = (const float*)d_in[7];
    const float* c0_wr   = (const float*)d_in[8];
    const float* c0_ci   = (const float*)d_in[9];
    const float* c0_rv   = (const float*)d_in[10];
    const float* r1_w    = (const float*)d_in[11];
    const float* r1_b    = (const float*)d_in[12];
    const float* c1_wr   = (const float*)d_in[13];
    const float* c1_ci   = (const float*)d_in[14];
    const int*   w_src   = (const int*)d_in[15];
    const int*   w_dst   = (const int*)d_in[16];
    const int*   c_src   = (const int*)d_in[17];
    const int*   c_dst   = (const int*)d_in[18];
    const int*   r_src   = (const int*)d_in[19];
    const int*   r_dst   = (const int*)d_in[20];

    // ---------------- workspace layout (d_ws) ----------------
    const size_t P768 = (size_t)P_NODES * 768;

    u16* big_A0 = (u16*)d_ws;              // P x 768: [h_p | agg_w0 | agg_c0]
    u16* big_A1 = big_A0 + P768;           // P x 768: [relu_p | agg_w1 | agg_c1]
    u16* x_bf   = big_A1 + P768;           // P x 128
    u16* wt_lin = x_bf + (size_t)P_NODES * IN_CH;   // 256 x 128
    u16* wt_l0p = wt_lin + 32768;          // 256 x 768
    u16* wt_l0a = wt_l0p + 196608;         // 256 x 512
    u16* wt_l1  = wt_l0a + 131072;         // 349 x 768
    float* inv_w = (float*)(wt_l1 + 268032 + 64);
    float* inv_c = inv_w + P_NODES;
    float* inv_r = inv_c + P_NODES;

    int* ip    = (int*)(inv_r + A_NODES);
    int* deg_w = ip;                 ip += P_NODES;
    int* deg_c = ip;                 ip += P_NODES;
    int* deg_r = ip;                 ip += A_NODES;
    int* ptr_w = ip;                 ip += P_NODES + 1;
    int* ptr_c = ip;                 ip += P_NODES + 1;
    int* ptr_r = ip;                 ip += A_NODES + 1;
    int* cur_w = ip;                 ip += P_NODES;
    int* cur_c = ip;                 ip += P_NODES;
    int* cur_r = ip;                 ip += A_NODES;
    int* idx_w = ip;                 ip += NE_W;
    int* idx_c = ip;                 ip += NE_C;
    int* idx_r = ip;                 ip += NE_W;
    int* blk   = ip;                 ip += 3 * 256;

    // ---------------- d_out-resident scratch (dead before final GEMM) ------
    u16* big_A0a  = (u16*)d_out;                         // A x 512: [emb_bf | agg_r0]
    u16* out_a_bf = big_A0a + (size_t)A_NODES * 512;     // A x 256
    float* logits = (float*)d_out;                       // P x 349 (final)

    // ---------------- prep: converts + weight transposes ----------------
    {
        int n = P_NODES * IN_CH / 4 + A_NODES * H_CH / 4;
        prep_convert<<<(n + 255) / 256, 256, 0, stream>>>(x_paper, x_bf, emb_a, big_A0a);
    }
    transpose_all<<<(628480 + 255) / 256, 256, 0, stream>>>(
        lin_w, r0p_w, c0_wr, c0_ci, r0a_w, c0_rv, r1_w, c1_wr, c1_ci,
        wt_lin, wt_l0p, wt_l0a, wt_l1);

    // ---------------- CSR builds ----------------
    hipMemsetAsync(deg_w, 0, (size_t)(2 * P_NODES + A_NODES) * sizeof(int), stream);
    deg3_kernel<<<(NE_C + 255) / 256, 256, 0, stream>>>(w_dst, c_dst, r_dst, deg_w, deg_c, deg_r);
    {
        dim3 ga((P_NODES + SCAN_BS - 1) / SCAN_BS, 3);
        scan_a3<<<ga, SCAN_BS, 0, stream>>>(deg_w, deg_c, deg_r, ptr_w, ptr_c, ptr_r, blk);
        scan_b3<<<3, SCAN_BS, 0, stream>>>(blk);
        dim3 gc((P_NODES + 255) / 256, 3);
        scan_c3<<<gc, 256, 0, stream>>>(deg_w, deg_c, deg_r, ptr_w, ptr_c, ptr_r, blk,
                                        cur_w, cur_c, cur_r, inv_w, inv_c, inv_r);
    }
    fill3_kernel<<<(NE_C + 255) / 256, 256, 0, stream>>>(
        w_src, w_dst, c_src, c_dst, r_src, r_dst, cur_w, cur_c, cur_r, idx_w, idx_c, idx_r);

    // ---------------- fused pipeline ----------------
    auto gat = [&](const u16* T, int ldt, const int* ptr, const int* idx,
                   const float* inv, u16* out, int ldo, int R) {
        gather_bf16<<<(R + 7) / 8, 256, 0, stream>>>(T, ldt, ptr, idx, inv, out, ldo, R);
    };

    // h_p = x @ lin_w + b -> big_A0 cols [0:256)
    {
        dim3 grid(2, (P_NODES + 127) / 128);
        mfma_gemm<true, false><<<grid, 256, 0, stream>>>(
            x_bf, IN_CH, wt_lin, 128, lin_b, big_A0, 768, P_NODES, H_CH, IN_CH);
    }
    gat(big_A0a, 512, ptr_w, idx_w, inv_w, big_A0 + 256, 768, P_NODES);   // agg_w0 = mean_w(emb)
    gat(big_A0, 768, ptr_c, idx_c, inv_c, big_A0 + 512, 768, P_NODES);    // agg_c0 = mean_c(h_p)
    gat(big_A0, 768, ptr_r, idx_r, inv_r, big_A0a + 256, 512, A_NODES);   // agg_r0 = mean_r(h_p)

    // relu_p = relu(big_A0 @ [r0p; c0wr; c0ci] + b) -> big_A1 cols [0:256)
    {
        dim3 grid(2, (P_NODES + 127) / 128);
        mfma_gemm<true, true><<<grid, 256, 0, stream>>>(
            big_A0, 768, wt_l0p, 768, r0p_b, big_A1, 768, P_NODES, H_CH, 768);
    }
    // relu_a = relu(big_A0a @ [r0a; c0rv] + b) -> out_a_bf
    {
        dim3 grid(2, (A_NODES + 127) / 128);
        mfma_gemm<true, true><<<grid, 256, 0, stream>>>(
            big_A0a, 512, wt_l0a, 512, r0a_b, out_a_bf, 256, A_NODES, H_CH, 512);
    }
    gat(out_a_bf, 256, ptr_w, idx_w, inv_w, big_A1 + 256, 768, P_NODES);  // agg_w1
    gat(big_A1, 768, ptr_c, idx_c, inv_c, big_A1 + 512, 768, P_NODES);    // agg_c1

    // logits = big_A1 @ [r1; c1wr; c1ci] + b (fp32, overwrites d_out scratch)
    {
        dim3 grid(3, (P_NODES + 127) / 128);
        mfma_gemm<false, false><<<grid, 256, 0, stream>>>(
            big_A1, 768, wt_l1, 768, r1_b, logits, OUT_CH, P_NODES, OUT_CH, 768);
    }

    // ---------------- log_softmax in place ----------------
    log_softmax_kernel<<<P_NODES, 64, 0, stream>>>(logits);
}